// Round 4
// baseline (1066.992 us; speedup 1.0000x reference)
//
#include <hip/hip_runtime.h>
#include <math.h>

#define NN 100000
#define DH 128
#define DOUT 64
#define FILL_PASSES 4

typedef __attribute__((ext_vector_type(8))) short bf16x8;
typedef __attribute__((ext_vector_type(4))) float f32x4;

__device__ __forceinline__ short f2bf(float f) {
  unsigned u = __float_as_uint(f);
  unsigned r = (u + 0x7fffu + ((u >> 16) & 1u)) >> 16;
  return (short)r;
}

// ---------------------------------------------------------------------------
// Edge-index dtype detector (int64 reference vs int32 harness doc).
// ---------------------------------------------------------------------------
__global__ __launch_bounds__(256) void detect_kernel(const int* __restrict__ ei, int E,
                                                     int* __restrict__ flag) {
  const long long* e64 = (const long long*)ei;
  int lim = E < 1024 ? E : 1024;
  int ok = 1;
  for (int i = threadIdx.x; i < lim; i += 256) {
    long long v = e64[i];
    if (v < 0 || v >= NN) ok = 0;
  }
  __shared__ int s_ok;
  if (threadIdx.x == 0) s_ok = 1;
  __syncthreads();
  if (!ok) atomicAnd(&s_ok, 0);
  __syncthreads();
  if (threadIdx.x == 0) *flag = s_ok;
}

__device__ __forceinline__ int edge_at(const int* __restrict__ ei, int is64, size_t pos) {
  return is64 ? (int)(((const long long*)ei)[pos]) : ei[pos];
}

// ---------------------------------------------------------------------------
// One pass over edges: pack to int2 {src,dst} AND build degree histogram
// (int atomics into L2-resident 400 KB array).
// ---------------------------------------------------------------------------
__global__ __launch_bounds__(256) void convert_deg_kernel(const int* __restrict__ ei, int E,
                                                          const int* __restrict__ flag,
                                                          int2* __restrict__ edges,
                                                          int* __restrict__ degi) {
  int e = blockIdx.x * 256 + threadIdx.x;
  if (e >= E) return;
  int is64 = *flag;
  int src = edge_at(ei, is64, (size_t)e);
  int dst = edge_at(ei, is64, (size_t)E + e);
  edges[e] = make_int2(src, dst);
  atomicAdd(&degi[dst], 1);
}

// ---------------------------------------------------------------------------
// Exclusive scan of degi -> row_ptr. Single block, 1024 thr x 4 elems/thr.
// ---------------------------------------------------------------------------
__global__ __launch_bounds__(1024) void scan_kernel(const int* __restrict__ degi,
                                                    int* __restrict__ row_ptr) {
  __shared__ int warp_sums[16];
  __shared__ int s_offset;
  int lane = threadIdx.x & 63;
  int wid = threadIdx.x >> 6;
  if (threadIdx.x == 0) s_offset = 0;
  __syncthreads();
  for (int base = 0; base < NN; base += 4096) {
    int i0 = base + threadIdx.x * 4;
    int v0 = (i0 + 0 < NN) ? degi[i0 + 0] : 0;
    int v1 = (i0 + 1 < NN) ? degi[i0 + 1] : 0;
    int v2 = (i0 + 2 < NN) ? degi[i0 + 2] : 0;
    int v3 = (i0 + 3 < NN) ? degi[i0 + 3] : 0;
    int tot = v0 + v1 + v2 + v3;
    int sv = tot;
#pragma unroll
    for (int o = 1; o < 64; o <<= 1) {
      int t = __shfl_up(sv, o, 64);
      if (lane >= o) sv += t;
    }
    if (lane == 63) warp_sums[wid] = sv;
    __syncthreads();
    if (wid == 0 && lane < 16) {
      int ws = warp_sums[lane];
#pragma unroll
      for (int o = 1; o < 16; o <<= 1) {
        int t = __shfl_up(ws, o, 16);
        if (lane >= o) ws += t;
      }
      warp_sums[lane] = ws;
    }
    __syncthreads();
    int wave_off = (wid == 0) ? 0 : warp_sums[wid - 1];
    int excl = s_offset + wave_off + sv - tot;
    if (i0 + 0 < NN) row_ptr[i0 + 0] = excl;
    if (i0 + 1 < NN) row_ptr[i0 + 1] = excl + v0;
    if (i0 + 2 < NN) row_ptr[i0 + 2] = excl + v0 + v1;
    if (i0 + 3 < NN) row_ptr[i0 + 3] = excl + v0 + v1 + v2;
    __syncthreads();
    if (threadIdx.x == 1023) s_offset = excl + tot;
    __syncthreads();
  }
}

// ---------------------------------------------------------------------------
// Windowed CSR fill: pass p only places edges whose dst is in window p, so
// col writes land in a ~1.6 MB L2-resident region -> dense line writeback
// instead of 64B-per-dword scatter. row_ptr doubles as cursor (ends at end).
// ---------------------------------------------------------------------------
__global__ __launch_bounds__(256) void fill_kernel(const int2* __restrict__ edges, int E,
                                                   int nb, int* __restrict__ row_ptr,
                                                   int* __restrict__ col) {
  int pass = blockIdx.x / nb;
  int blk = blockIdx.x - pass * nb;
  int e = blk * 256 + threadIdx.x;
  if (e >= E) return;
  int2 sd = edges[e];
  const int WIN = (NN + FILL_PASSES - 1) / FILL_PASSES;
  if ((unsigned)(sd.y - pass * WIN) < (unsigned)WIN) {
    int pos = atomicAdd(&row_ptr[sd.y], 1);
    col[pos] = sd.x;
  }
}

// ---------------------------------------------------------------------------
// Gather-based mean aggregation: 32 lanes per node, float4 per lane.
// ---------------------------------------------------------------------------
__global__ __launch_bounds__(256) void gather_kernel(const float* __restrict__ feat,
                                                     const int* __restrict__ col,
                                                     const int* __restrict__ row_end,
                                                     const int* __restrict__ degi,
                                                     float* __restrict__ outp) {
  int tid = blockIdx.x * 256 + threadIdx.x;
  int n = tid >> 5;
  if (n >= NN) return;
  int g = tid & 31;
  int d = degi[n];
  int start = row_end[n] - d;
  float4 acc = make_float4(0.f, 0.f, 0.f, 0.f);
#pragma unroll 4
  for (int i = 0; i < d; i++) {
    int src = col[start + i];
    float4 v = ((const float4*)(feat + (size_t)src * DH))[g];
    acc.x += v.x; acc.y += v.y; acc.z += v.z; acc.w += v.w;
  }
  float inv = 1.0f / (float)max(d, 1);
  ((float4*)(outp + (size_t)n * DH))[g] =
      make_float4(acc.x * inv, acc.y * inv, acc.z * inv, acc.w * inv);
}

// ---------------------------------------------------------------------------
// Weight conversion: Wb1[128][256] = [W1l | W1r] bf16, Wb2[64][256] likewise.
// ---------------------------------------------------------------------------
__global__ __launch_bounds__(256) void convw_kernel(const float* __restrict__ W1l,
                                                    const float* __restrict__ W1r,
                                                    const float* __restrict__ W2l,
                                                    const float* __restrict__ W2r,
                                                    unsigned short* __restrict__ Wb1,
                                                    unsigned short* __restrict__ Wb2) {
  int tid = blockIdx.x * 256 + threadIdx.x;
  if (tid < 128 * 256) {
    int n = tid >> 8, k = tid & 255;
    float v = (k < 128) ? W1l[n * 128 + k] : W1r[n * 128 + (k - 128)];
    Wb1[tid] = (unsigned short)f2bf(v);
  } else if (tid < 128 * 256 + 64 * 256) {
    int t2 = tid - 128 * 256;
    int n = t2 >> 8, k = t2 & 255;
    float v = (k < 128) ? W2l[n * 128 + k] : W2r[n * 128 + (k - 128)];
    Wb2[t2] = (unsigned short)f2bf(v);
  }
}

// ---------------------------------------------------------------------------
// Layer 1 MFMA GEMM + fused BN column partials (h is in registers anyway).
// Per-block partials -> part[blk][{sum,sq}][128], no atomic contention.
// ---------------------------------------------------------------------------
__global__ __launch_bounds__(256) void gemm1_mfma(const float* __restrict__ s,
                                                  const float* __restrict__ x,
                                                  const unsigned short* __restrict__ Wb,
                                                  const float* __restrict__ b1l,
                                                  float* __restrict__ h,
                                                  float* __restrict__ part) {
  __shared__ float sred[2][4][DH];
  int w = threadIdx.x >> 6;
  int l = threadIdx.x & 63;
  int rowbase = blockIdx.x * 64 + w * 16;
  int m = l & 15;
  int q = l >> 4;
  int row = rowbase + m;
  int rl = row < NN ? row : NN - 1;
  f32x4 acc[8];
#pragma unroll
  for (int t = 0; t < 8; t++) acc[t] = (f32x4){0.f, 0.f, 0.f, 0.f};
#pragma unroll
  for (int ks = 0; ks < 8; ks++) {
    const float* src = (ks < 4) ? (s + (size_t)rl * DH + ks * 32 + q * 8)
                                : (x + (size_t)rl * DH + (ks - 4) * 32 + q * 8);
    float4 f0 = ((const float4*)src)[0];
    float4 f1 = ((const float4*)src)[1];
    bf16x8 af;
    af[0] = f2bf(f0.x); af[1] = f2bf(f0.y); af[2] = f2bf(f0.z); af[3] = f2bf(f0.w);
    af[4] = f2bf(f1.x); af[5] = f2bf(f1.y); af[6] = f2bf(f1.z); af[7] = f2bf(f1.w);
#pragma unroll
    for (int t = 0; t < 8; t++) {
      const unsigned short* bp = Wb + (size_t)(t * 16 + m) * 256 + ks * 32 + q * 8;
      bf16x8 bf = *(const bf16x8*)bp;
      acc[t] = __builtin_amdgcn_mfma_f32_16x16x32_bf16(af, bf, acc[t], 0, 0, 0);
    }
  }
  // C layout: col = t*16 + m, row = rowbase + q*4 + r
  float psum[8], psq[8];
#pragma unroll
  for (int t = 0; t < 8; t++) { psum[t] = 0.f; psq[t] = 0.f; }
#pragma unroll
  for (int t = 0; t < 8; t++) {
    float bias = b1l[t * 16 + m];
#pragma unroll
    for (int r = 0; r < 4; r++) {
      int rr = rowbase + q * 4 + r;
      if (rr < NN) {
        float vv = acc[t][r] + bias;
        h[(size_t)rr * DH + t * 16 + m] = vv;
        psum[t] += vv;
        psq[t] += vv * vv;
      }
    }
  }
  // reduce the 4 q-lanes holding the same column
#pragma unroll
  for (int t = 0; t < 8; t++) {
    psum[t] += __shfl_xor(psum[t], 16, 64);
    psum[t] += __shfl_xor(psum[t], 32, 64);
    psq[t] += __shfl_xor(psq[t], 16, 64);
    psq[t] += __shfl_xor(psq[t], 32, 64);
  }
  if (q == 0) {
#pragma unroll
    for (int t = 0; t < 8; t++) {
      sred[0][w][t * 16 + m] = psum[t];
      sred[1][w][t * 16 + m] = psq[t];
    }
  }
  __syncthreads();
  int tid = threadIdx.x;
  if (tid < DH) {
    float v = sred[0][0][tid] + sred[0][1][tid] + sred[0][2][tid] + sred[0][3][tid];
    part[((size_t)blockIdx.x * 2 + 0) * DH + tid] = v;
  } else if (tid < 2 * DH) {
    int c = tid - DH;
    float v = sred[1][0][c] + sred[1][1][c] + sred[1][2][c] + sred[1][3][c];
    part[((size_t)blockIdx.x * 2 + 1) * DH + c] = v;
  }
}

// Reduce per-block partials -> sums / sumsq (coalesced, single block).
__global__ __launch_bounds__(256) void bn_reduce_kernel(const float* __restrict__ part,
                                                        int nblk,
                                                        float* __restrict__ sums,
                                                        float* __restrict__ sumsq) {
  int tid = threadIdx.x;
  if (tid < DH) {
    float s = 0.f;
    for (int b = 0; b < nblk; b++) s += part[((size_t)b * 2 + 0) * DH + tid];
    sums[tid] = s;
  } else {
    int c = tid - DH;
    float s = 0.f;
    for (int b = 0; b < nblk; b++) s += part[((size_t)b * 2 + 1) * DH + c];
    sumsq[c] = s;
  }
}

__global__ __launch_bounds__(256) void bn_apply_kernel(float* __restrict__ h,
                                                       const float* __restrict__ sums,
                                                       const float* __restrict__ sumsq,
                                                       const float* __restrict__ gamma,
                                                       const float* __restrict__ beta) {
  int tid = blockIdx.x * 256 + threadIdx.x;
  int c = tid & (DH - 1);
  float mean = sums[c] * (1.0f / NN);
  float var = sumsq[c] * (1.0f / NN) - mean * mean;
  float scl = gamma[c] * rsqrtf(var + 1e-5f);
  float sh = beta[c] - mean * scl;
  float v = h[tid] * scl + sh;
  h[tid] = fmaxf(v, 0.0f);
}

// ---------------------------------------------------------------------------
// Layer 2 MFMA GEMM + fused log_softmax. A = [s2 | h], N=64 (4 col-tiles).
// ---------------------------------------------------------------------------
__global__ __launch_bounds__(256) void gemm2_mfma(const float* __restrict__ s,
                                                  const float* __restrict__ hin,
                                                  const unsigned short* __restrict__ Wb,
                                                  const float* __restrict__ b2l,
                                                  float* __restrict__ out) {
  int w = threadIdx.x >> 6;
  int l = threadIdx.x & 63;
  int rowbase = blockIdx.x * 64 + w * 16;
  int m = l & 15;
  int q = l >> 4;
  int row = rowbase + m;
  int rl = row < NN ? row : NN - 1;
  f32x4 acc[4];
#pragma unroll
  for (int t = 0; t < 4; t++) acc[t] = (f32x4){0.f, 0.f, 0.f, 0.f};
#pragma unroll
  for (int ks = 0; ks < 8; ks++) {
    const float* src = (ks < 4) ? (s + (size_t)rl * DH + ks * 32 + q * 8)
                                : (hin + (size_t)rl * DH + (ks - 4) * 32 + q * 8);
    float4 f0 = ((const float4*)src)[0];
    float4 f1 = ((const float4*)src)[1];
    bf16x8 af;
    af[0] = f2bf(f0.x); af[1] = f2bf(f0.y); af[2] = f2bf(f0.z); af[3] = f2bf(f0.w);
    af[4] = f2bf(f1.x); af[5] = f2bf(f1.y); af[6] = f2bf(f1.z); af[7] = f2bf(f1.w);
#pragma unroll
    for (int t = 0; t < 4; t++) {
      const unsigned short* bp = Wb + (size_t)(t * 16 + m) * 256 + ks * 32 + q * 8;
      bf16x8 bf = *(const bf16x8*)bp;
      acc[t] = __builtin_amdgcn_mfma_f32_16x16x32_bf16(af, bf, acc[t], 0, 0, 0);
    }
  }
  float v[4][4];
#pragma unroll
  for (int t = 0; t < 4; t++) {
    float bias = b2l[t * 16 + m];
#pragma unroll
    for (int r = 0; r < 4; r++) v[t][r] = acc[t][r] + bias;
  }
#pragma unroll
  for (int r = 0; r < 4; r++) {
    float mx = fmaxf(fmaxf(v[0][r], v[1][r]), fmaxf(v[2][r], v[3][r]));
    mx = fmaxf(mx, __shfl_xor(mx, 1, 64));
    mx = fmaxf(mx, __shfl_xor(mx, 2, 64));
    mx = fmaxf(mx, __shfl_xor(mx, 4, 64));
    mx = fmaxf(mx, __shfl_xor(mx, 8, 64));
    float se = __expf(v[0][r] - mx) + __expf(v[1][r] - mx) +
               __expf(v[2][r] - mx) + __expf(v[3][r] - mx);
    se += __shfl_xor(se, 1, 64);
    se += __shfl_xor(se, 2, 64);
    se += __shfl_xor(se, 4, 64);
    se += __shfl_xor(se, 8, 64);
    float lse = mx + logf(se);
    int rr = rowbase + q * 4 + r;
    if (rr < NN) {
#pragma unroll
      for (int t = 0; t < 4; t++)
        out[(size_t)rr * DOUT + t * 16 + m] = v[t][r] - lse;
    }
  }
}

// ---------------------------------------------------------------------------
extern "C" void kernel_launch(void* const* d_in, const int* in_sizes, int n_in,
                              void* d_out, int out_size, void* d_ws, size_t ws_size,
                              hipStream_t stream) {
  const float* x = (const float*)d_in[0];
  const int* ei = (const int*)d_in[1];
  const float* W1l = (const float*)d_in[2];
  const float* b1l = (const float*)d_in[3];
  const float* W1r = (const float*)d_in[4];
  const float* gamma = (const float*)d_in[5];
  const float* beta = (const float*)d_in[6];
  const float* W2l = (const float*)d_in[7];
  const float* b2l = (const float*)d_in[8];
  const float* W2r = (const float*)d_in[9];
  float* out = (float*)d_out;
  int E = in_sizes[1] / 2;
  int nblk1 = (NN + 63) / 64;

  // workspace: s_buf[N*128] (reused as int2 edges[E] before gather) | h_buf[N*128]
  //            | degi[N] | row_ptr[N] | col[E] | part[nblk1*2*128]
  //            | sums[128] | sumsq[128] | flag | Wb1 | Wb2
  float* s_buf = (float*)d_ws;
  float* h_buf = s_buf + (size_t)NN * DH;
  int* degi = (int*)(h_buf + (size_t)NN * DH);
  int* row_ptr = degi + NN;
  int* col = row_ptr + NN;
  float* part = (float*)(col + E);
  float* sums = part + (size_t)nblk1 * 2 * DH;
  float* sumsq = sums + DH;
  int* flag = (int*)(sumsq + DH);
  unsigned short* Wb1 = (unsigned short*)(flag + 1);
  unsigned short* Wb2 = Wb1 + 128 * 256;
  int2* edges = (int2*)s_buf;  // dead until first gather overwrites it

  hipMemsetAsync(degi, 0, NN * sizeof(int), stream);

  detect_kernel<<<1, 256, 0, stream>>>(ei, E, flag);
  convw_kernel<<<192, 256, 0, stream>>>(W1l, W1r, W2l, W2r, Wb1, Wb2);
  convert_deg_kernel<<<(E + 255) / 256, 256, 0, stream>>>(ei, E, flag, edges, degi);
  scan_kernel<<<1, 1024, 0, stream>>>(degi, row_ptr);
  int nb = (E + 255) / 256;
  fill_kernel<<<FILL_PASSES * nb, 256, 0, stream>>>(edges, E, nb, row_ptr, col);
  gather_kernel<<<(NN * 32 + 255) / 256, 256, 0, stream>>>(x, col, row_ptr, degi, s_buf);
  gemm1_mfma<<<nblk1, 256, 0, stream>>>(s_buf, x, Wb1, b1l, h_buf, part);
  bn_reduce_kernel<<<1, 256, 0, stream>>>(part, nblk1, sums, sumsq);
  bn_apply_kernel<<<(NN * DH) / 256, 256, 0, stream>>>(h_buf, sums, sumsq, gamma, beta);
  gather_kernel<<<(NN * 32 + 255) / 256, 256, 0, stream>>>(h_buf, col, row_ptr, degi, s_buf);
  gemm2_mfma<<<(NN + 63) / 64, 256, 0, stream>>>(s_buf, h_buf, Wb2, b2l, out);
}

// Round 5
// 609.011 us; speedup vs baseline: 1.7520x; 1.7520x over previous
//
#include <hip/hip_runtime.h>
#include <math.h>

#define NN 100000
#define DH 128
#define DOUT 64
#define FILL_PASSES 4

typedef __attribute__((ext_vector_type(8))) short bf16x8;
typedef __attribute__((ext_vector_type(4))) float f32x4;

__device__ __forceinline__ short f2bf(float f) {
  unsigned u = __float_as_uint(f);
  unsigned r = (u + 0x7fffu + ((u >> 16) & 1u)) >> 16;
  return (short)r;
}

// ---------------------------------------------------------------------------
// Edge-index dtype detector (int64 reference vs int32 harness doc).
// ---------------------------------------------------------------------------
__global__ __launch_bounds__(256) void detect_kernel(const int* __restrict__ ei, int E,
                                                     int* __restrict__ flag) {
  const long long* e64 = (const long long*)ei;
  int lim = E < 1024 ? E : 1024;
  int ok = 1;
  for (int i = threadIdx.x; i < lim; i += 256) {
    long long v = e64[i];
    if (v < 0 || v >= NN) ok = 0;
  }
  __shared__ int s_ok;
  if (threadIdx.x == 0) s_ok = 1;
  __syncthreads();
  if (!ok) atomicAnd(&s_ok, 0);
  __syncthreads();
  if (threadIdx.x == 0) *flag = s_ok;
}

__device__ __forceinline__ int edge_at(const int* __restrict__ ei, int is64, size_t pos) {
  return is64 ? (int)(((const long long*)ei)[pos]) : ei[pos];
}

// ---------------------------------------------------------------------------
// One pass over edges: pack to int2 {src,dst} AND build degree histogram.
// ---------------------------------------------------------------------------
__global__ __launch_bounds__(256) void convert_deg_kernel(const int* __restrict__ ei, int E,
                                                          const int* __restrict__ flag,
                                                          int2* __restrict__ edges,
                                                          int* __restrict__ degi) {
  int e = blockIdx.x * 256 + threadIdx.x;
  if (e >= E) return;
  int is64 = *flag;
  int src = edge_at(ei, is64, (size_t)e);
  int dst = edge_at(ei, is64, (size_t)E + e);
  edges[e] = make_int2(src, dst);
  atomicAdd(&degi[dst], 1);
}

// ---------------------------------------------------------------------------
// Exclusive scan of degi -> row_ptr. Single block, 1024 thr x 4 elems/thr.
// ---------------------------------------------------------------------------
__global__ __launch_bounds__(1024) void scan_kernel(const int* __restrict__ degi,
                                                    int* __restrict__ row_ptr) {
  __shared__ int warp_sums[16];
  __shared__ int s_offset;
  int lane = threadIdx.x & 63;
  int wid = threadIdx.x >> 6;
  if (threadIdx.x == 0) s_offset = 0;
  __syncthreads();
  for (int base = 0; base < NN; base += 4096) {
    int i0 = base + threadIdx.x * 4;
    int v0 = (i0 + 0 < NN) ? degi[i0 + 0] : 0;
    int v1 = (i0 + 1 < NN) ? degi[i0 + 1] : 0;
    int v2 = (i0 + 2 < NN) ? degi[i0 + 2] : 0;
    int v3 = (i0 + 3 < NN) ? degi[i0 + 3] : 0;
    int tot = v0 + v1 + v2 + v3;
    int sv = tot;
#pragma unroll
    for (int o = 1; o < 64; o <<= 1) {
      int t = __shfl_up(sv, o, 64);
      if (lane >= o) sv += t;
    }
    if (lane == 63) warp_sums[wid] = sv;
    __syncthreads();
    if (wid == 0 && lane < 16) {
      int ws = warp_sums[lane];
#pragma unroll
      for (int o = 1; o < 16; o <<= 1) {
        int t = __shfl_up(ws, o, 16);
        if (lane >= o) ws += t;
      }
      warp_sums[lane] = ws;
    }
    __syncthreads();
    int wave_off = (wid == 0) ? 0 : warp_sums[wid - 1];
    int excl = s_offset + wave_off + sv - tot;
    if (i0 + 0 < NN) row_ptr[i0 + 0] = excl;
    if (i0 + 1 < NN) row_ptr[i0 + 1] = excl + v0;
    if (i0 + 2 < NN) row_ptr[i0 + 2] = excl + v0 + v1;
    if (i0 + 3 < NN) row_ptr[i0 + 3] = excl + v0 + v1 + v2;
    __syncthreads();
    if (threadIdx.x == 1023) s_offset = excl + tot;
    __syncthreads();
  }
}

// ---------------------------------------------------------------------------
// Windowed CSR fill (L2-resident col window -> dense line writeback).
// ---------------------------------------------------------------------------
__global__ __launch_bounds__(256) void fill_kernel(const int2* __restrict__ edges, int E,
                                                   int nb, int* __restrict__ row_ptr,
                                                   int* __restrict__ col) {
  int pass = blockIdx.x / nb;
  int blk = blockIdx.x - pass * nb;
  int e = blk * 256 + threadIdx.x;
  if (e >= E) return;
  int2 sd = edges[e];
  const int WIN = (NN + FILL_PASSES - 1) / FILL_PASSES;
  if ((unsigned)(sd.y - pass * WIN) < (unsigned)WIN) {
    int pos = atomicAdd(&row_ptr[sd.y], 1);
    col[pos] = sd.x;
  }
}

// ---------------------------------------------------------------------------
// Gather mean-agg, 128-dim rows: 32 lanes per node, float4 per lane.
// ---------------------------------------------------------------------------
__global__ __launch_bounds__(256) void gather128_kernel(const float* __restrict__ feat,
                                                        const int* __restrict__ col,
                                                        const int* __restrict__ row_end,
                                                        const int* __restrict__ degi,
                                                        float* __restrict__ outp) {
  int tid = blockIdx.x * 256 + threadIdx.x;
  int n = tid >> 5;
  if (n >= NN) return;
  int g = tid & 31;
  int d = degi[n];
  int start = row_end[n] - d;
  float4 acc = make_float4(0.f, 0.f, 0.f, 0.f);
#pragma unroll 4
  for (int i = 0; i < d; i++) {
    int src = col[start + i];
    float4 v = ((const float4*)(feat + (size_t)src * DH))[g];
    acc.x += v.x; acc.y += v.y; acc.z += v.z; acc.w += v.w;
  }
  float inv = 1.0f / (float)max(d, 1);
  ((float4*)(outp + (size_t)n * DH))[g] =
      make_float4(acc.x * inv, acc.y * inv, acc.z * inv, acc.w * inv);
}

// ---------------------------------------------------------------------------
// Gather mean-agg, 64-dim rows: 16 lanes per node, float4 per lane.
// ---------------------------------------------------------------------------
__global__ __launch_bounds__(256) void gather64_kernel(const float* __restrict__ feat,
                                                       const int* __restrict__ col,
                                                       const int* __restrict__ row_end,
                                                       const int* __restrict__ degi,
                                                       float* __restrict__ outp) {
  int tid = blockIdx.x * 256 + threadIdx.x;
  int n = tid >> 4;
  if (n >= NN) return;
  int g = tid & 15;
  int d = degi[n];
  int start = row_end[n] - d;
  float4 acc = make_float4(0.f, 0.f, 0.f, 0.f);
#pragma unroll 4
  for (int i = 0; i < d; i++) {
    int src = col[start + i];
    float4 v = ((const float4*)(feat + (size_t)src * DOUT))[g];
    acc.x += v.x; acc.y += v.y; acc.z += v.z; acc.w += v.w;
  }
  float inv = 1.0f / (float)max(d, 1);
  ((float4*)(outp + (size_t)n * DOUT))[g] =
      make_float4(acc.x * inv, acc.y * inv, acc.z * inv, acc.w * inv);
}

// ---------------------------------------------------------------------------
// Weight conversion: Wb1[128][256]=[W1l|W1r], Wb2l[64][128], Wb2r[64][128].
// ---------------------------------------------------------------------------
__global__ __launch_bounds__(256) void convw_kernel(const float* __restrict__ W1l,
                                                    const float* __restrict__ W1r,
                                                    const float* __restrict__ W2l,
                                                    const float* __restrict__ W2r,
                                                    unsigned short* __restrict__ Wb1,
                                                    unsigned short* __restrict__ Wb2l,
                                                    unsigned short* __restrict__ Wb2r) {
  int tid = blockIdx.x * 256 + threadIdx.x;
  if (tid < 128 * 256) {
    int n = tid >> 8, k = tid & 255;
    float v = (k < 128) ? W1l[n * 128 + k] : W1r[n * 128 + (k - 128)];
    Wb1[tid] = (unsigned short)f2bf(v);
  } else if (tid < 128 * 256 + 64 * 128) {
    int t2 = tid - 128 * 256;
    Wb2l[t2] = (unsigned short)f2bf(W2l[t2]);
  } else if (tid < 128 * 256 + 2 * 64 * 128) {
    int t2 = tid - 128 * 256 - 64 * 128;
    Wb2r[t2] = (unsigned short)f2bf(W2r[t2]);
  }
}

// ---------------------------------------------------------------------------
// Layer 1 MFMA GEMM + fused BN column sums via per-block LDS + atomics.
// ---------------------------------------------------------------------------
__global__ __launch_bounds__(256) void gemm1_mfma(const float* __restrict__ s,
                                                  const float* __restrict__ x,
                                                  const unsigned short* __restrict__ Wb,
                                                  const float* __restrict__ b1l,
                                                  float* __restrict__ h,
                                                  float* __restrict__ sums,
                                                  float* __restrict__ sumsq) {
  __shared__ float sred[2][4][DH];
  int w = threadIdx.x >> 6;
  int l = threadIdx.x & 63;
  int rowbase = blockIdx.x * 64 + w * 16;
  int m = l & 15;
  int q = l >> 4;
  int row = rowbase + m;
  int rl = row < NN ? row : NN - 1;
  f32x4 acc[8];
#pragma unroll
  for (int t = 0; t < 8; t++) acc[t] = (f32x4){0.f, 0.f, 0.f, 0.f};
#pragma unroll
  for (int ks = 0; ks < 8; ks++) {
    const float* src = (ks < 4) ? (s + (size_t)rl * DH + ks * 32 + q * 8)
                                : (x + (size_t)rl * DH + (ks - 4) * 32 + q * 8);
    float4 f0 = ((const float4*)src)[0];
    float4 f1 = ((const float4*)src)[1];
    bf16x8 af;
    af[0] = f2bf(f0.x); af[1] = f2bf(f0.y); af[2] = f2bf(f0.z); af[3] = f2bf(f0.w);
    af[4] = f2bf(f1.x); af[5] = f2bf(f1.y); af[6] = f2bf(f1.z); af[7] = f2bf(f1.w);
#pragma unroll
    for (int t = 0; t < 8; t++) {
      const unsigned short* bp = Wb + (size_t)(t * 16 + m) * 256 + ks * 32 + q * 8;
      bf16x8 bf = *(const bf16x8*)bp;
      acc[t] = __builtin_amdgcn_mfma_f32_16x16x32_bf16(af, bf, acc[t], 0, 0, 0);
    }
  }
  // C layout: col = t*16 + m, row = rowbase + q*4 + r
  float psum[8], psq[8];
#pragma unroll
  for (int t = 0; t < 8; t++) { psum[t] = 0.f; psq[t] = 0.f; }
#pragma unroll
  for (int t = 0; t < 8; t++) {
    float bias = b1l[t * 16 + m];
#pragma unroll
    for (int r = 0; r < 4; r++) {
      int rr = rowbase + q * 4 + r;
      if (rr < NN) {
        float vv = acc[t][r] + bias;
        h[(size_t)rr * DH + t * 16 + m] = vv;
        psum[t] += vv;
        psq[t] += vv * vv;
      }
    }
  }
#pragma unroll
  for (int t = 0; t < 8; t++) {
    psum[t] += __shfl_xor(psum[t], 16, 64);
    psum[t] += __shfl_xor(psum[t], 32, 64);
    psq[t] += __shfl_xor(psq[t], 16, 64);
    psq[t] += __shfl_xor(psq[t], 32, 64);
  }
  if (q == 0) {
#pragma unroll
    for (int t = 0; t < 8; t++) {
      sred[0][w][t * 16 + m] = psum[t];
      sred[1][w][t * 16 + m] = psq[t];
    }
  }
  __syncthreads();
  int tid = threadIdx.x;
  if (tid < DH) {
    atomicAdd(&sums[tid], sred[0][0][tid] + sred[0][1][tid] + sred[0][2][tid] + sred[0][3][tid]);
  } else if (tid < 2 * DH) {
    int c = tid - DH;
    atomicAdd(&sumsq[c], sred[1][0][c] + sred[1][1][c] + sred[1][2][c] + sred[1][3][c]);
  }
}

// stats -> per-column scale/shift (tiny).
__global__ __launch_bounds__(128) void bn_prep_kernel(const float* __restrict__ sums,
                                                      const float* __restrict__ sumsq,
                                                      const float* __restrict__ gamma,
                                                      const float* __restrict__ beta,
                                                      float* __restrict__ scl,
                                                      float* __restrict__ sh) {
  int c = threadIdx.x;
  float mean = sums[c] * (1.0f / NN);
  float var = sumsq[c] * (1.0f / NN) - mean * mean;
  float s = gamma[c] * rsqrtf(var + 1e-5f);
  scl[c] = s;
  sh[c] = beta[c] - mean * s;
}

// ---------------------------------------------------------------------------
// BN+ReLU applied in registers from raw h, A-fragment builder (shared by
// z_mfma and gemm2). k-chunk = ks*32 + q*8 .. +7.
// ---------------------------------------------------------------------------
__device__ __forceinline__ bf16x8 bn_frag(const float* __restrict__ hrow,
                                          const float* __restrict__ scl,
                                          const float* __restrict__ sh,
                                          int k0) {
  float4 f0 = ((const float4*)(hrow + k0))[0];
  float4 f1 = ((const float4*)(hrow + k0))[1];
  float4 s0 = ((const float4*)(scl + k0))[0];
  float4 s1 = ((const float4*)(scl + k0))[1];
  float4 h0 = ((const float4*)(sh + k0))[0];
  float4 h1 = ((const float4*)(sh + k0))[1];
  bf16x8 af;
  af[0] = f2bf(fmaxf(f0.x * s0.x + h0.x, 0.f));
  af[1] = f2bf(fmaxf(f0.y * s0.y + h0.y, 0.f));
  af[2] = f2bf(fmaxf(f0.z * s0.z + h0.z, 0.f));
  af[3] = f2bf(fmaxf(f0.w * s0.w + h0.w, 0.f));
  af[4] = f2bf(fmaxf(f1.x * s1.x + h1.x, 0.f));
  af[5] = f2bf(fmaxf(f1.y * s1.y + h1.y, 0.f));
  af[6] = f2bf(fmaxf(f1.z * s1.z + h1.z, 0.f));
  af[7] = f2bf(fmaxf(f1.w * s1.w + h1.w, 0.f));
  return af;
}

// ---------------------------------------------------------------------------
// z = relu(bn(h)) @ W2l^T   [N x 64], K=128. Transform-before-aggregate.
// ---------------------------------------------------------------------------
__global__ __launch_bounds__(256) void z_mfma(const float* __restrict__ hin,
                                              const float* __restrict__ scl,
                                              const float* __restrict__ sh,
                                              const unsigned short* __restrict__ Wb2l,
                                              float* __restrict__ z) {
  int w = threadIdx.x >> 6;
  int l = threadIdx.x & 63;
  int rowbase = blockIdx.x * 64 + w * 16;
  int m = l & 15;
  int q = l >> 4;
  int row = rowbase + m;
  int rl = row < NN ? row : NN - 1;
  const float* hrow = hin + (size_t)rl * DH;
  f32x4 acc[4];
#pragma unroll
  for (int t = 0; t < 4; t++) acc[t] = (f32x4){0.f, 0.f, 0.f, 0.f};
#pragma unroll
  for (int ks = 0; ks < 4; ks++) {
    bf16x8 af = bn_frag(hrow, scl, sh, ks * 32 + q * 8);
#pragma unroll
    for (int t = 0; t < 4; t++) {
      const unsigned short* bp = Wb2l + (size_t)(t * 16 + m) * DH + ks * 32 + q * 8;
      bf16x8 bf = *(const bf16x8*)bp;
      acc[t] = __builtin_amdgcn_mfma_f32_16x16x32_bf16(af, bf, acc[t], 0, 0, 0);
    }
  }
#pragma unroll
  for (int t = 0; t < 4; t++) {
#pragma unroll
    for (int r = 0; r < 4; r++) {
      int rr = rowbase + q * 4 + r;
      if (rr < NN) z[(size_t)rr * DOUT + t * 16 + m] = acc[t][r];
    }
  }
}

// ---------------------------------------------------------------------------
// Layer 2: out = z_agg + relu(bn(h)) @ W2r^T + b2, then log_softmax.
// ---------------------------------------------------------------------------
__global__ __launch_bounds__(256) void gemm2_mfma(const float* __restrict__ hin,
                                                  const float* __restrict__ scl,
                                                  const float* __restrict__ sh,
                                                  const float* __restrict__ zagg,
                                                  const unsigned short* __restrict__ Wb2r,
                                                  const float* __restrict__ b2l,
                                                  float* __restrict__ out) {
  int w = threadIdx.x >> 6;
  int l = threadIdx.x & 63;
  int rowbase = blockIdx.x * 64 + w * 16;
  int m = l & 15;
  int q = l >> 4;
  int row = rowbase + m;
  int rl = row < NN ? row : NN - 1;
  const float* hrow = hin + (size_t)rl * DH;
  f32x4 acc[4];
#pragma unroll
  for (int t = 0; t < 4; t++) acc[t] = (f32x4){0.f, 0.f, 0.f, 0.f};
#pragma unroll
  for (int ks = 0; ks < 4; ks++) {
    bf16x8 af = bn_frag(hrow, scl, sh, ks * 32 + q * 8);
#pragma unroll
    for (int t = 0; t < 4; t++) {
      const unsigned short* bp = Wb2r + (size_t)(t * 16 + m) * DH + ks * 32 + q * 8;
      bf16x8 bf = *(const bf16x8*)bp;
      acc[t] = __builtin_amdgcn_mfma_f32_16x16x32_bf16(af, bf, acc[t], 0, 0, 0);
    }
  }
  float v[4][4];
#pragma unroll
  for (int t = 0; t < 4; t++) {
    float bias = b2l[t * 16 + m];
#pragma unroll
    for (int r = 0; r < 4; r++) {
      int rr = rowbase + q * 4 + r;
      float zg = (rr < NN) ? zagg[(size_t)rr * DOUT + t * 16 + m] : 0.f;
      v[t][r] = acc[t][r] + zg + bias;
    }
  }
#pragma unroll
  for (int r = 0; r < 4; r++) {
    float mx = fmaxf(fmaxf(v[0][r], v[1][r]), fmaxf(v[2][r], v[3][r]));
    mx = fmaxf(mx, __shfl_xor(mx, 1, 64));
    mx = fmaxf(mx, __shfl_xor(mx, 2, 64));
    mx = fmaxf(mx, __shfl_xor(mx, 4, 64));
    mx = fmaxf(mx, __shfl_xor(mx, 8, 64));
    float se = __expf(v[0][r] - mx) + __expf(v[1][r] - mx) +
               __expf(v[2][r] - mx) + __expf(v[3][r] - mx);
    se += __shfl_xor(se, 1, 64);
    se += __shfl_xor(se, 2, 64);
    se += __shfl_xor(se, 4, 64);
    se += __shfl_xor(se, 8, 64);
    float lse = mx + logf(se);
    int rr = rowbase + q * 4 + r;
    if (rr < NN) {
#pragma unroll
      for (int t = 0; t < 4; t++)
        out[(size_t)rr * DOUT + t * 16 + m] = v[t][r] - lse;
    }
  }
}

// ---------------------------------------------------------------------------
extern "C" void kernel_launch(void* const* d_in, const int* in_sizes, int n_in,
                              void* d_out, int out_size, void* d_ws, size_t ws_size,
                              hipStream_t stream) {
  const float* x = (const float*)d_in[0];
  const int* ei = (const int*)d_in[1];
  const float* W1l = (const float*)d_in[2];
  const float* b1l = (const float*)d_in[3];
  const float* W1r = (const float*)d_in[4];
  const float* gamma = (const float*)d_in[5];
  const float* beta = (const float*)d_in[6];
  const float* W2l = (const float*)d_in[7];
  const float* b2l = (const float*)d_in[8];
  const float* W2r = (const float*)d_in[9];
  float* out = (float*)d_out;
  int E = in_sizes[1] / 2;
  int nblk1 = (NN + 63) / 64;

  // workspace: s_buf[N*128] (edges int2[E] -> s -> z[N*64]+zagg[N*64]) |
  //   h_buf[N*128] | degi[N] | row_ptr[N] | col[E] | sums/sumsq/scl/sh[128ea]
  //   | flag | Wb1[128*256] | Wb2l[64*128] | Wb2r[64*128]
  float* s_buf = (float*)d_ws;
  float* h_buf = s_buf + (size_t)NN * DH;
  int* degi = (int*)(h_buf + (size_t)NN * DH);
  int* row_ptr = degi + NN;
  int* col = row_ptr + NN;
  float* sums = (float*)(col + E);
  float* sumsq = sums + DH;
  float* scl = sumsq + DH;
  float* sh = scl + DH;
  int* flag = (int*)(sh + DH);
  unsigned short* Wb1 = (unsigned short*)(flag + 1);
  unsigned short* Wb2l = Wb1 + 128 * 256;
  unsigned short* Wb2r = Wb2l + 64 * 128;
  int2* edges = (int2*)s_buf;           // dead after fill
  float* z = s_buf;                     // dead after gemm1; reused for z
  float* zagg = s_buf + (size_t)NN * DOUT;

  hipMemsetAsync(degi, 0, NN * sizeof(int), stream);
  hipMemsetAsync(sums, 0, 2 * DH * sizeof(float), stream);

  detect_kernel<<<1, 256, 0, stream>>>(ei, E, flag);
  convw_kernel<<<192, 256, 0, stream>>>(W1l, W1r, W2l, W2r, Wb1, Wb2l, Wb2r);
  convert_deg_kernel<<<(E + 255) / 256, 256, 0, stream>>>(ei, E, flag, edges, degi);
  scan_kernel<<<1, 1024, 0, stream>>>(degi, row_ptr);
  int nb = (E + 255) / 256;
  fill_kernel<<<FILL_PASSES * nb, 256, 0, stream>>>(edges, E, nb, row_ptr, col);
  gather128_kernel<<<(NN * 32 + 255) / 256, 256, 0, stream>>>(x, col, row_ptr, degi, s_buf);
  gemm1_mfma<<<nblk1, 256, 0, stream>>>(s_buf, x, Wb1, b1l, h_buf, sums, sumsq);
  bn_prep_kernel<<<1, 128, 0, stream>>>(sums, sumsq, gamma, beta, scl, sh);
  z_mfma<<<nblk1, 256, 0, stream>>>(h_buf, scl, sh, Wb2l, z);
  gather64_kernel<<<(NN * 16 + 255) / 256, 256, 0, stream>>>(z, col, row_ptr, degi, zagg);
  gemm2_mfma<<<nblk1, 256, 0, stream>>>(h_buf, scl, sh, zagg, Wb2r, b2l, out);
}

// Round 6
// 533.409 us; speedup vs baseline: 2.0003x; 1.1417x over previous
//
#include <hip/hip_runtime.h>
#include <math.h>

#define NN 100000
#define DH 128
#define DOUT 64
#define FILL_PASSES 4

typedef __attribute__((ext_vector_type(8))) short bf16x8;
typedef __attribute__((ext_vector_type(4))) float f32x4;
typedef unsigned short ushort_t;

__device__ __forceinline__ short f2bf(float f) {
  unsigned u = __float_as_uint(f);
  unsigned r = (u + 0x7fffu + ((u >> 16) & 1u)) >> 16;
  return (short)r;
}
__device__ __forceinline__ float bf2f(short b) {
  return __uint_as_float(((unsigned)(unsigned short)b) << 16);
}

// ---------------------------------------------------------------------------
// Edge-index dtype detector (int64 reference vs int32 harness doc).
// ---------------------------------------------------------------------------
__global__ __launch_bounds__(256) void detect_kernel(const int* __restrict__ ei, int E,
                                                     int* __restrict__ flag) {
  const long long* e64 = (const long long*)ei;
  int lim = E < 1024 ? E : 1024;
  int ok = 1;
  for (int i = threadIdx.x; i < lim; i += 256) {
    long long v = e64[i];
    if (v < 0 || v >= NN) ok = 0;
  }
  __shared__ int s_ok;
  if (threadIdx.x == 0) s_ok = 1;
  __syncthreads();
  if (!ok) atomicAnd(&s_ok, 0);
  __syncthreads();
  if (threadIdx.x == 0) *flag = s_ok;
}

__device__ __forceinline__ int edge_at(const int* __restrict__ ei, int is64, size_t pos) {
  return is64 ? (int)(((const long long*)ei)[pos]) : ei[pos];
}

// ---------------------------------------------------------------------------
// x (fp32) -> x_bf16, 8 elems/thread.
// ---------------------------------------------------------------------------
__global__ __launch_bounds__(256) void convx_kernel(const float* __restrict__ x,
                                                    ushort_t* __restrict__ xb) {
  size_t i = ((size_t)blockIdx.x * 256 + threadIdx.x) * 8;
  if (i >= (size_t)NN * DH) return;
  float4 f0 = ((const float4*)(x + i))[0];
  float4 f1 = ((const float4*)(x + i))[1];
  bf16x8 o;
  o[0] = f2bf(f0.x); o[1] = f2bf(f0.y); o[2] = f2bf(f0.z); o[3] = f2bf(f0.w);
  o[4] = f2bf(f1.x); o[5] = f2bf(f1.y); o[6] = f2bf(f1.z); o[7] = f2bf(f1.w);
  *(bf16x8*)(xb + i) = o;
}

// ---------------------------------------------------------------------------
// One pass over edges: pack to int2 {src,dst} AND build degree histogram.
// ---------------------------------------------------------------------------
__global__ __launch_bounds__(256) void convert_deg_kernel(const int* __restrict__ ei, int E,
                                                          const int* __restrict__ flag,
                                                          int2* __restrict__ edges,
                                                          int* __restrict__ degi) {
  int e = blockIdx.x * 256 + threadIdx.x;
  if (e >= E) return;
  int is64 = *flag;
  int src = edge_at(ei, is64, (size_t)e);
  int dst = edge_at(ei, is64, (size_t)E + e);
  edges[e] = make_int2(src, dst);
  atomicAdd(&degi[dst], 1);
}

// ---------------------------------------------------------------------------
// Exclusive scan of degi -> row_ptr. Single block, 1024 thr x 4 elems/thr.
// ---------------------------------------------------------------------------
__global__ __launch_bounds__(1024) void scan_kernel(const int* __restrict__ degi,
                                                    int* __restrict__ row_ptr) {
  __shared__ int warp_sums[16];
  __shared__ int s_offset;
  int lane = threadIdx.x & 63;
  int wid = threadIdx.x >> 6;
  if (threadIdx.x == 0) s_offset = 0;
  __syncthreads();
  for (int base = 0; base < NN; base += 4096) {
    int i0 = base + threadIdx.x * 4;
    int v0 = (i0 + 0 < NN) ? degi[i0 + 0] : 0;
    int v1 = (i0 + 1 < NN) ? degi[i0 + 1] : 0;
    int v2 = (i0 + 2 < NN) ? degi[i0 + 2] : 0;
    int v3 = (i0 + 3 < NN) ? degi[i0 + 3] : 0;
    int tot = v0 + v1 + v2 + v3;
    int sv = tot;
#pragma unroll
    for (int o = 1; o < 64; o <<= 1) {
      int t = __shfl_up(sv, o, 64);
      if (lane >= o) sv += t;
    }
    if (lane == 63) warp_sums[wid] = sv;
    __syncthreads();
    if (wid == 0 && lane < 16) {
      int ws = warp_sums[lane];
#pragma unroll
      for (int o = 1; o < 16; o <<= 1) {
        int t = __shfl_up(ws, o, 16);
        if (lane >= o) ws += t;
      }
      warp_sums[lane] = ws;
    }
    __syncthreads();
    int wave_off = (wid == 0) ? 0 : warp_sums[wid - 1];
    int excl = s_offset + wave_off + sv - tot;
    if (i0 + 0 < NN) row_ptr[i0 + 0] = excl;
    if (i0 + 1 < NN) row_ptr[i0 + 1] = excl + v0;
    if (i0 + 2 < NN) row_ptr[i0 + 2] = excl + v0 + v1;
    if (i0 + 3 < NN) row_ptr[i0 + 3] = excl + v0 + v1 + v2;
    __syncthreads();
    if (threadIdx.x == 1023) s_offset = excl + tot;
    __syncthreads();
  }
}

// ---------------------------------------------------------------------------
// Windowed CSR fill (L2-resident col window -> dense line writeback).
// ---------------------------------------------------------------------------
__global__ __launch_bounds__(256) void fill_kernel(const int2* __restrict__ edges, int E,
                                                   int nb, int* __restrict__ row_ptr,
                                                   int* __restrict__ col) {
  int pass = blockIdx.x / nb;
  int blk = blockIdx.x - pass * nb;
  int e = blk * 256 + threadIdx.x;
  if (e >= E) return;
  int2 sd = edges[e];
  const int WIN = (NN + FILL_PASSES - 1) / FILL_PASSES;
  if ((unsigned)(sd.y - pass * WIN) < (unsigned)WIN) {
    int pos = atomicAdd(&row_ptr[sd.y], 1);
    col[pos] = sd.x;
  }
}

// ---------------------------------------------------------------------------
// Gather mean-agg, 128-dim bf16 rows: 16 lanes/node, bf16x8 (16B) per lane.
// fp32 accumulate, bf16 write.
// ---------------------------------------------------------------------------
__global__ __launch_bounds__(256) void gather128_kernel(const ushort_t* __restrict__ feat,
                                                        const int* __restrict__ col,
                                                        const int* __restrict__ row_end,
                                                        const int* __restrict__ degi,
                                                        ushort_t* __restrict__ outp) {
  int tid = blockIdx.x * 256 + threadIdx.x;
  int n = tid >> 4;
  if (n >= NN) return;
  int g = tid & 15;
  int d = degi[n];
  int start = row_end[n] - d;
  float acc[8];
#pragma unroll
  for (int j = 0; j < 8; j++) acc[j] = 0.f;
#pragma unroll 4
  for (int i = 0; i < d; i++) {
    int src = col[start + i];
    bf16x8 v = *(const bf16x8*)(feat + (size_t)src * DH + g * 8);
#pragma unroll
    for (int j = 0; j < 8; j++) acc[j] += bf2f(v[j]);
  }
  float inv = 1.0f / (float)max(d, 1);
  bf16x8 o;
#pragma unroll
  for (int j = 0; j < 8; j++) o[j] = f2bf(acc[j] * inv);
  *(bf16x8*)(outp + (size_t)n * DH + g * 8) = o;
}

// ---------------------------------------------------------------------------
// Gather mean-agg, 64-dim bf16 rows: 8 lanes/node, bf16x8 per lane.
// ---------------------------------------------------------------------------
__global__ __launch_bounds__(256) void gather64_kernel(const ushort_t* __restrict__ feat,
                                                       const int* __restrict__ col,
                                                       const int* __restrict__ row_end,
                                                       const int* __restrict__ degi,
                                                       ushort_t* __restrict__ outp) {
  int tid = blockIdx.x * 256 + threadIdx.x;
  int n = tid >> 3;
  if (n >= NN) return;
  int g = tid & 7;
  int d = degi[n];
  int start = row_end[n] - d;
  float acc[8];
#pragma unroll
  for (int j = 0; j < 8; j++) acc[j] = 0.f;
#pragma unroll 4
  for (int i = 0; i < d; i++) {
    int src = col[start + i];
    bf16x8 v = *(const bf16x8*)(feat + (size_t)src * DOUT + g * 8);
#pragma unroll
    for (int j = 0; j < 8; j++) acc[j] += bf2f(v[j]);
  }
  float inv = 1.0f / (float)max(d, 1);
  bf16x8 o;
#pragma unroll
  for (int j = 0; j < 8; j++) o[j] = f2bf(acc[j] * inv);
  *(bf16x8*)(outp + (size_t)n * DOUT + g * 8) = o;
}

// ---------------------------------------------------------------------------
// Weight conversion: Wb1[128][256]=[W1l|W1r], Wb2l[64][128], Wb2r[64][128].
// ---------------------------------------------------------------------------
__global__ __launch_bounds__(256) void convw_kernel(const float* __restrict__ W1l,
                                                    const float* __restrict__ W1r,
                                                    const float* __restrict__ W2l,
                                                    const float* __restrict__ W2r,
                                                    ushort_t* __restrict__ Wb1,
                                                    ushort_t* __restrict__ Wb2l,
                                                    ushort_t* __restrict__ Wb2r) {
  int tid = blockIdx.x * 256 + threadIdx.x;
  if (tid < 128 * 256) {
    int n = tid >> 8, k = tid & 255;
    float v = (k < 128) ? W1l[n * 128 + k] : W1r[n * 128 + (k - 128)];
    Wb1[tid] = (ushort_t)f2bf(v);
  } else if (tid < 128 * 256 + 64 * 128) {
    int t2 = tid - 128 * 256;
    Wb2l[t2] = (ushort_t)f2bf(W2l[t2]);
  } else if (tid < 128 * 256 + 2 * 64 * 128) {
    int t2 = tid - 128 * 256 - 64 * 128;
    Wb2r[t2] = (ushort_t)f2bf(W2r[t2]);
  }
}

// ---------------------------------------------------------------------------
// Layer 1 MFMA GEMM: A = [s_bf16 | x_bf16] fragments read directly (no cvt).
// Epilogue: h stored bf16 (stats in fp32), BN column sums via LDS + atomics.
// ---------------------------------------------------------------------------
__global__ __launch_bounds__(256) void gemm1_mfma(const ushort_t* __restrict__ s,
                                                  const ushort_t* __restrict__ x,
                                                  const ushort_t* __restrict__ Wb,
                                                  const float* __restrict__ b1l,
                                                  ushort_t* __restrict__ h,
                                                  float* __restrict__ sums,
                                                  float* __restrict__ sumsq) {
  __shared__ float sred[2][4][DH];
  int w = threadIdx.x >> 6;
  int l = threadIdx.x & 63;
  int rowbase = blockIdx.x * 64 + w * 16;
  int m = l & 15;
  int q = l >> 4;
  int row = rowbase + m;
  int rl = row < NN ? row : NN - 1;
  f32x4 acc[8];
#pragma unroll
  for (int t = 0; t < 8; t++) acc[t] = (f32x4){0.f, 0.f, 0.f, 0.f};
#pragma unroll
  for (int ks = 0; ks < 8; ks++) {
    const ushort_t* src = (ks < 4) ? (s + (size_t)rl * DH + ks * 32 + q * 8)
                                   : (x + (size_t)rl * DH + (ks - 4) * 32 + q * 8);
    bf16x8 af = *(const bf16x8*)src;
#pragma unroll
    for (int t = 0; t < 8; t++) {
      const ushort_t* bp = Wb + (size_t)(t * 16 + m) * 256 + ks * 32 + q * 8;
      bf16x8 bf = *(const bf16x8*)bp;
      acc[t] = __builtin_amdgcn_mfma_f32_16x16x32_bf16(af, bf, acc[t], 0, 0, 0);
    }
  }
  // C layout: col = t*16 + m, row = rowbase + q*4 + r
  float psum[8], psq[8];
#pragma unroll
  for (int t = 0; t < 8; t++) { psum[t] = 0.f; psq[t] = 0.f; }
#pragma unroll
  for (int t = 0; t < 8; t++) {
    float bias = b1l[t * 16 + m];
#pragma unroll
    for (int r = 0; r < 4; r++) {
      int rr = rowbase + q * 4 + r;
      if (rr < NN) {
        float vv = acc[t][r] + bias;
        h[(size_t)rr * DH + t * 16 + m] = (ushort_t)f2bf(vv);
        psum[t] += vv;
        psq[t] += vv * vv;
      }
    }
  }
#pragma unroll
  for (int t = 0; t < 8; t++) {
    psum[t] += __shfl_xor(psum[t], 16, 64);
    psum[t] += __shfl_xor(psum[t], 32, 64);
    psq[t] += __shfl_xor(psq[t], 16, 64);
    psq[t] += __shfl_xor(psq[t], 32, 64);
  }
  if (q == 0) {
#pragma unroll
    for (int t = 0; t < 8; t++) {
      sred[0][w][t * 16 + m] = psum[t];
      sred[1][w][t * 16 + m] = psq[t];
    }
  }
  __syncthreads();
  int tid = threadIdx.x;
  if (tid < DH) {
    atomicAdd(&sums[tid], sred[0][0][tid] + sred[0][1][tid] + sred[0][2][tid] + sred[0][3][tid]);
  } else if (tid < 2 * DH) {
    int c = tid - DH;
    atomicAdd(&sumsq[c], sred[1][0][c] + sred[1][1][c] + sred[1][2][c] + sred[1][3][c]);
  }
}

// stats -> per-column scale/shift (tiny).
__global__ __launch_bounds__(128) void bn_prep_kernel(const float* __restrict__ sums,
                                                      const float* __restrict__ sumsq,
                                                      const float* __restrict__ gamma,
                                                      const float* __restrict__ beta,
                                                      float* __restrict__ scl,
                                                      float* __restrict__ sh) {
  int c = threadIdx.x;
  float mean = sums[c] * (1.0f / NN);
  float var = sumsq[c] * (1.0f / NN) - mean * mean;
  float s = gamma[c] * rsqrtf(var + 1e-5f);
  scl[c] = s;
  sh[c] = beta[c] - mean * s;
}

// ---------------------------------------------------------------------------
// BN+ReLU A-fragment from bf16 h. k-chunk = k0..k0+7.
// ---------------------------------------------------------------------------
__device__ __forceinline__ bf16x8 bn_frag(const ushort_t* __restrict__ hrow,
                                          const float* __restrict__ scl,
                                          const float* __restrict__ sh,
                                          int k0) {
  bf16x8 hv = *(const bf16x8*)(hrow + k0);
  float4 s0 = ((const float4*)(scl + k0))[0];
  float4 s1 = ((const float4*)(scl + k0))[1];
  float4 h0 = ((const float4*)(sh + k0))[0];
  float4 h1 = ((const float4*)(sh + k0))[1];
  bf16x8 af;
  af[0] = f2bf(fmaxf(bf2f(hv[0]) * s0.x + h0.x, 0.f));
  af[1] = f2bf(fmaxf(bf2f(hv[1]) * s0.y + h0.y, 0.f));
  af[2] = f2bf(fmaxf(bf2f(hv[2]) * s0.z + h0.z, 0.f));
  af[3] = f2bf(fmaxf(bf2f(hv[3]) * s0.w + h0.w, 0.f));
  af[4] = f2bf(fmaxf(bf2f(hv[4]) * s1.x + h1.x, 0.f));
  af[5] = f2bf(fmaxf(bf2f(hv[5]) * s1.y + h1.y, 0.f));
  af[6] = f2bf(fmaxf(bf2f(hv[6]) * s1.z + h1.z, 0.f));
  af[7] = f2bf(fmaxf(bf2f(hv[7]) * s1.w + h1.w, 0.f));
  return af;
}

// ---------------------------------------------------------------------------
// z = relu(bn(h)) @ W2l^T   [N x 64] bf16 out, K=128.
// ---------------------------------------------------------------------------
__global__ __launch_bounds__(256) void z_mfma(const ushort_t* __restrict__ hin,
                                              const float* __restrict__ scl,
                                              const float* __restrict__ sh,
                                              const ushort_t* __restrict__ Wb2l,
                                              ushort_t* __restrict__ z) {
  int w = threadIdx.x >> 6;
  int l = threadIdx.x & 63;
  int rowbase = blockIdx.x * 64 + w * 16;
  int m = l & 15;
  int q = l >> 4;
  int row = rowbase + m;
  int rl = row < NN ? row : NN - 1;
  const ushort_t* hrow = hin + (size_t)rl * DH;
  f32x4 acc[4];
#pragma unroll
  for (int t = 0; t < 4; t++) acc[t] = (f32x4){0.f, 0.f, 0.f, 0.f};
#pragma unroll
  for (int ks = 0; ks < 4; ks++) {
    bf16x8 af = bn_frag(hrow, scl, sh, ks * 32 + q * 8);
#pragma unroll
    for (int t = 0; t < 4; t++) {
      const ushort_t* bp = Wb2l + (size_t)(t * 16 + m) * DH + ks * 32 + q * 8;
      bf16x8 bf = *(const bf16x8*)bp;
      acc[t] = __builtin_amdgcn_mfma_f32_16x16x32_bf16(af, bf, acc[t], 0, 0, 0);
    }
  }
#pragma unroll
  for (int t = 0; t < 4; t++) {
#pragma unroll
    for (int r = 0; r < 4; r++) {
      int rr = rowbase + q * 4 + r;
      if (rr < NN) z[(size_t)rr * DOUT + t * 16 + m] = (ushort_t)f2bf(acc[t][r]);
    }
  }
}

// ---------------------------------------------------------------------------
// Layer 2: out = zagg + relu(bn(h)) @ W2r^T + b2, then log_softmax.
// ---------------------------------------------------------------------------
__global__ __launch_bounds__(256) void gemm2_mfma(const ushort_t* __restrict__ hin,
                                                  const float* __restrict__ scl,
                                                  const float* __restrict__ sh,
                                                  const ushort_t* __restrict__ zagg,
                                                  const ushort_t* __restrict__ Wb2r,
                                                  const float* __restrict__ b2l,
                                                  float* __restrict__ out) {
  int w = threadIdx.x >> 6;
  int l = threadIdx.x & 63;
  int rowbase = blockIdx.x * 64 + w * 16;
  int m = l & 15;
  int q = l >> 4;
  int row = rowbase + m;
  int rl = row < NN ? row : NN - 1;
  const ushort_t* hrow = hin + (size_t)rl * DH;
  f32x4 acc[4];
#pragma unroll
  for (int t = 0; t < 4; t++) acc[t] = (f32x4){0.f, 0.f, 0.f, 0.f};
#pragma unroll
  for (int ks = 0; ks < 4; ks++) {
    bf16x8 af = bn_frag(hrow, scl, sh, ks * 32 + q * 8);
#pragma unroll
    for (int t = 0; t < 4; t++) {
      const ushort_t* bp = Wb2r + (size_t)(t * 16 + m) * DH + ks * 32 + q * 8;
      bf16x8 bf = *(const bf16x8*)bp;
      acc[t] = __builtin_amdgcn_mfma_f32_16x16x32_bf16(af, bf, acc[t], 0, 0, 0);
    }
  }
  float v[4][4];
#pragma unroll
  for (int t = 0; t < 4; t++) {
    float bias = b2l[t * 16 + m];
#pragma unroll
    for (int r = 0; r < 4; r++) {
      int rr = rowbase + q * 4 + r;
      float zg = (rr < NN) ? bf2f((short)zagg[(size_t)rr * DOUT + t * 16 + m]) : 0.f;
      v[t][r] = acc[t][r] + zg + bias;
    }
  }
#pragma unroll
  for (int r = 0; r < 4; r++) {
    float mx = fmaxf(fmaxf(v[0][r], v[1][r]), fmaxf(v[2][r], v[3][r]));
    mx = fmaxf(mx, __shfl_xor(mx, 1, 64));
    mx = fmaxf(mx, __shfl_xor(mx, 2, 64));
    mx = fmaxf(mx, __shfl_xor(mx, 4, 64));
    mx = fmaxf(mx, __shfl_xor(mx, 8, 64));
    float se = __expf(v[0][r] - mx) + __expf(v[1][r] - mx) +
               __expf(v[2][r] - mx) + __expf(v[3][r] - mx);
    se += __shfl_xor(se, 1, 64);
    se += __shfl_xor(se, 2, 64);
    se += __shfl_xor(se, 4, 64);
    se += __shfl_xor(se, 8, 64);
    float lse = mx + logf(se);
    int rr = rowbase + q * 4 + r;
    if (rr < NN) {
#pragma unroll
      for (int t = 0; t < 4; t++)
        out[(size_t)rr * DOUT + t * 16 + m] = v[t][r] - lse;
    }
  }
}

// ---------------------------------------------------------------------------
extern "C" void kernel_launch(void* const* d_in, const int* in_sizes, int n_in,
                              void* d_out, int out_size, void* d_ws, size_t ws_size,
                              hipStream_t stream) {
  const float* x = (const float*)d_in[0];
  const int* ei = (const int*)d_in[1];
  const float* W1l = (const float*)d_in[2];
  const float* b1l = (const float*)d_in[3];
  const float* W1r = (const float*)d_in[4];
  const float* gamma = (const float*)d_in[5];
  const float* beta = (const float*)d_in[6];
  const float* W2l = (const float*)d_in[7];
  const float* b2l = (const float*)d_in[8];
  const float* W2r = (const float*)d_in[9];
  float* out = (float*)d_out;
  int E = in_sizes[1] / 2;
  int nblk1 = (NN + 63) / 64;

  // workspace (~110 MB):
  //   u0: union { edges int2[E] (12.8 MB, dead after fill) |
  //               z_bf16[N*64] + zagg_bf16[N*64] (25.6 MB) }  -> 25.6 MB
  //   x_bf16[N*128] 25.6 | s_bf16[N*128] 25.6 | h_bf16[N*128] 25.6
  //   degi[N] | row_ptr[N] | col[E] | sums/sumsq/scl/sh | flag | Wb1/Wb2l/Wb2r
  char* p = (char*)d_ws;
  int2* edges = (int2*)p;
  ushort_t* z_bf = (ushort_t*)p;
  ushort_t* zagg_bf = z_bf + (size_t)NN * DOUT;
  p += (size_t)NN * DOUT * 2 * sizeof(ushort_t);  // 25.6 MB (covers edges' 12.8)
  ushort_t* x_bf = (ushort_t*)p;  p += (size_t)NN * DH * sizeof(ushort_t);
  ushort_t* s_bf = (ushort_t*)p;  p += (size_t)NN * DH * sizeof(ushort_t);
  ushort_t* h_bf = (ushort_t*)p;  p += (size_t)NN * DH * sizeof(ushort_t);
  int* degi = (int*)p;            p += NN * sizeof(int);
  int* row_ptr = (int*)p;         p += NN * sizeof(int);
  int* col = (int*)p;             p += (size_t)E * sizeof(int);
  float* sums = (float*)p;        p += DH * sizeof(float);
  float* sumsq = (float*)p;       p += DH * sizeof(float);
  float* scl = (float*)p;         p += DH * sizeof(float);
  float* sh = (float*)p;          p += DH * sizeof(float);
  int* flag = (int*)p;            p += 4 * sizeof(int);
  ushort_t* Wb1 = (ushort_t*)p;   p += 128 * 256 * sizeof(ushort_t);
  ushort_t* Wb2l = (ushort_t*)p;  p += 64 * 128 * sizeof(ushort_t);
  ushort_t* Wb2r = (ushort_t*)p;

  hipMemsetAsync(degi, 0, NN * sizeof(int), stream);
  hipMemsetAsync(sums, 0, 2 * DH * sizeof(float), stream);

  detect_kernel<<<1, 256, 0, stream>>>(ei, E, flag);
  convw_kernel<<<192, 256, 0, stream>>>(W1l, W1r, W2l, W2r, Wb1, Wb2l, Wb2r);
  convx_kernel<<<(NN * DH / 8 + 255) / 256, 256, 0, stream>>>(x, x_bf);
  convert_deg_kernel<<<(E + 255) / 256, 256, 0, stream>>>(ei, E, flag, edges, degi);
  scan_kernel<<<1, 1024, 0, stream>>>(degi, row_ptr);
  int nb = (E + 255) / 256;
  fill_kernel<<<FILL_PASSES * nb, 256, 0, stream>>>(edges, E, nb, row_ptr, col);
  gather128_kernel<<<(NN * 16 + 255) / 256, 256, 0, stream>>>(x_bf, col, row_ptr, degi, s_bf);
  gemm1_mfma<<<nblk1, 256, 0, stream>>>(s_bf, x_bf, Wb1, b1l, h_bf, sums, sumsq);
  bn_prep_kernel<<<1, 128, 0, stream>>>(sums, sumsq, gamma, beta, scl, sh);
  z_mfma<<<nblk1, 256, 0, stream>>>(h_bf, scl, sh, Wb2l, z_bf);
  gather64_kernel<<<(NN * 8 + 255) / 256, 256, 0, stream>>>(z_bf, col, row_ptr, degi, zagg_bf);
  gemm2_mfma<<<nblk1, 256, 0, stream>>>(h_bf, scl, sh, zagg_bf, Wb2r, b2l, out);
}

// Round 7
// 496.265 us; speedup vs baseline: 2.1500x; 1.0748x over previous
//
#include <hip/hip_runtime.h>
#include <math.h>

#define NN 100000
#define DH 128
#define DOUT 64
#define FILL_PASSES 4

typedef __attribute__((ext_vector_type(8))) short bf16x8;
typedef __attribute__((ext_vector_type(4))) float f32x4;
typedef unsigned short ushort_t;

__device__ __forceinline__ short f2bf(float f) {
  unsigned u = __float_as_uint(f);
  unsigned r = (u + 0x7fffu + ((u >> 16) & 1u)) >> 16;
  return (short)r;
}
__device__ __forceinline__ float bf2f(short b) {
  return __uint_as_float(((unsigned)(unsigned short)b) << 16);
}

// ---------------------------------------------------------------------------
// Edge-index dtype detector (int64 reference vs int32 harness doc).
// ---------------------------------------------------------------------------
__global__ __launch_bounds__(256) void detect_kernel(const int* __restrict__ ei, int E,
                                                     int* __restrict__ flag) {
  const long long* e64 = (const long long*)ei;
  int lim = E < 1024 ? E : 1024;
  int ok = 1;
  for (int i = threadIdx.x; i < lim; i += 256) {
    long long v = e64[i];
    if (v < 0 || v >= NN) ok = 0;
  }
  __shared__ int s_ok;
  if (threadIdx.x == 0) s_ok = 1;
  __syncthreads();
  if (!ok) atomicAnd(&s_ok, 0);
  __syncthreads();
  if (threadIdx.x == 0) *flag = s_ok;
}

__device__ __forceinline__ int edge_at(const int* __restrict__ ei, int is64, size_t pos) {
  return is64 ? (int)(((const long long*)ei)[pos]) : ei[pos];
}

// ---------------------------------------------------------------------------
// x (fp32) -> x_bf16, 8 elems/thread.
// ---------------------------------------------------------------------------
__global__ __launch_bounds__(256) void convx_kernel(const float* __restrict__ x,
                                                    ushort_t* __restrict__ xb) {
  size_t i = ((size_t)blockIdx.x * 256 + threadIdx.x) * 8;
  if (i >= (size_t)NN * DH) return;
  float4 f0 = ((const float4*)(x + i))[0];
  float4 f1 = ((const float4*)(x + i))[1];
  bf16x8 o;
  o[0] = f2bf(f0.x); o[1] = f2bf(f0.y); o[2] = f2bf(f0.z); o[3] = f2bf(f0.w);
  o[4] = f2bf(f1.x); o[5] = f2bf(f1.y); o[6] = f2bf(f1.z); o[7] = f2bf(f1.w);
  *(bf16x8*)(xb + i) = o;
}

// ---------------------------------------------------------------------------
// One pass over edges: pack to int2 {src,dst} AND build degree histogram.
// ---------------------------------------------------------------------------
__global__ __launch_bounds__(256) void convert_deg_kernel(const int* __restrict__ ei, int E,
                                                          const int* __restrict__ flag,
                                                          int2* __restrict__ edges,
                                                          int* __restrict__ degi) {
  int e = blockIdx.x * 256 + threadIdx.x;
  if (e >= E) return;
  int is64 = *flag;
  int src = edge_at(ei, is64, (size_t)e);
  int dst = edge_at(ei, is64, (size_t)E + e);
  edges[e] = make_int2(src, dst);
  atomicAdd(&degi[dst], 1);
}

// ---------------------------------------------------------------------------
// Exclusive scan of degi -> row_ptr. Single block, 1024 thr x 4 elems/thr.
// ---------------------------------------------------------------------------
__global__ __launch_bounds__(1024) void scan_kernel(const int* __restrict__ degi,
                                                    int* __restrict__ row_ptr) {
  __shared__ int warp_sums[16];
  __shared__ int s_offset;
  int lane = threadIdx.x & 63;
  int wid = threadIdx.x >> 6;
  if (threadIdx.x == 0) s_offset = 0;
  __syncthreads();
  for (int base = 0; base < NN; base += 4096) {
    int i0 = base + threadIdx.x * 4;
    int v0 = (i0 + 0 < NN) ? degi[i0 + 0] : 0;
    int v1 = (i0 + 1 < NN) ? degi[i0 + 1] : 0;
    int v2 = (i0 + 2 < NN) ? degi[i0 + 2] : 0;
    int v3 = (i0 + 3 < NN) ? degi[i0 + 3] : 0;
    int tot = v0 + v1 + v2 + v3;
    int sv = tot;
#pragma unroll
    for (int o = 1; o < 64; o <<= 1) {
      int t = __shfl_up(sv, o, 64);
      if (lane >= o) sv += t;
    }
    if (lane == 63) warp_sums[wid] = sv;
    __syncthreads();
    if (wid == 0 && lane < 16) {
      int ws = warp_sums[lane];
#pragma unroll
      for (int o = 1; o < 16; o <<= 1) {
        int t = __shfl_up(ws, o, 16);
        if (lane >= o) ws += t;
      }
      warp_sums[lane] = ws;
    }
    __syncthreads();
    int wave_off = (wid == 0) ? 0 : warp_sums[wid - 1];
    int excl = s_offset + wave_off + sv - tot;
    if (i0 + 0 < NN) row_ptr[i0 + 0] = excl;
    if (i0 + 1 < NN) row_ptr[i0 + 1] = excl + v0;
    if (i0 + 2 < NN) row_ptr[i0 + 2] = excl + v0 + v1;
    if (i0 + 3 < NN) row_ptr[i0 + 3] = excl + v0 + v1 + v2;
    __syncthreads();
    if (threadIdx.x == 1023) s_offset = excl + tot;
    __syncthreads();
  }
}

// ---------------------------------------------------------------------------
// Windowed CSR fill (L2-resident col window -> dense line writeback).
// ---------------------------------------------------------------------------
__global__ __launch_bounds__(256) void fill_kernel(const int2* __restrict__ edges, int E,
                                                   int nb, int* __restrict__ row_ptr,
                                                   int* __restrict__ col) {
  int pass = blockIdx.x / nb;
  int blk = blockIdx.x - pass * nb;
  int e = blk * 256 + threadIdx.x;
  if (e >= E) return;
  int2 sd = edges[e];
  const int WIN = (NN + FILL_PASSES - 1) / FILL_PASSES;
  if ((unsigned)(sd.y - pass * WIN) < (unsigned)WIN) {
    int pos = atomicAdd(&row_ptr[sd.y], 1);
    col[pos] = sd.x;
  }
}

// ---------------------------------------------------------------------------
// Gather mean-agg, 128-dim bf16 rows: 16 lanes/node, bf16x8 (16B) per lane.
// ---------------------------------------------------------------------------
__global__ __launch_bounds__(256) void gather128_kernel(const ushort_t* __restrict__ feat,
                                                        const int* __restrict__ col,
                                                        const int* __restrict__ row_end,
                                                        const int* __restrict__ degi,
                                                        ushort_t* __restrict__ outp) {
  int tid = blockIdx.x * 256 + threadIdx.x;
  int n = tid >> 4;
  if (n >= NN) return;
  int g = tid & 15;
  int d = degi[n];
  int start = row_end[n] - d;
  float acc[8];
#pragma unroll
  for (int j = 0; j < 8; j++) acc[j] = 0.f;
#pragma unroll 4
  for (int i = 0; i < d; i++) {
    int src = col[start + i];
    bf16x8 v = *(const bf16x8*)(feat + (size_t)src * DH + g * 8);
#pragma unroll
    for (int j = 0; j < 8; j++) acc[j] += bf2f(v[j]);
  }
  float inv = 1.0f / (float)max(d, 1);
  bf16x8 o;
#pragma unroll
  for (int j = 0; j < 8; j++) o[j] = f2bf(acc[j] * inv);
  *(bf16x8*)(outp + (size_t)n * DH + g * 8) = o;
}

// ---------------------------------------------------------------------------
// Gather mean-agg, 64-dim bf16 rows: 8 lanes/node, bf16x8 per lane.
// ---------------------------------------------------------------------------
__global__ __launch_bounds__(256) void gather64_kernel(const ushort_t* __restrict__ feat,
                                                       const int* __restrict__ col,
                                                       const int* __restrict__ row_end,
                                                       const int* __restrict__ degi,
                                                       ushort_t* __restrict__ outp) {
  int tid = blockIdx.x * 256 + threadIdx.x;
  int n = tid >> 3;
  if (n >= NN) return;
  int g = tid & 7;
  int d = degi[n];
  int start = row_end[n] - d;
  float acc[8];
#pragma unroll
  for (int j = 0; j < 8; j++) acc[j] = 0.f;
#pragma unroll 4
  for (int i = 0; i < d; i++) {
    int src = col[start + i];
    bf16x8 v = *(const bf16x8*)(feat + (size_t)src * DOUT + g * 8);
#pragma unroll
    for (int j = 0; j < 8; j++) acc[j] += bf2f(v[j]);
  }
  float inv = 1.0f / (float)max(d, 1);
  bf16x8 o;
#pragma unroll
  for (int j = 0; j < 8; j++) o[j] = f2bf(acc[j] * inv);
  *(bf16x8*)(outp + (size_t)n * DOUT + g * 8) = o;
}

// ---------------------------------------------------------------------------
// Weight conversion: Wb1[128][256]=[W1l|W1r], Wb2l[64][128], Wb2r[64][128].
// ---------------------------------------------------------------------------
__global__ __launch_bounds__(256) void convw_kernel(const float* __restrict__ W1l,
                                                    const float* __restrict__ W1r,
                                                    const float* __restrict__ W2l,
                                                    const float* __restrict__ W2r,
                                                    ushort_t* __restrict__ Wb1,
                                                    ushort_t* __restrict__ Wb2l,
                                                    ushort_t* __restrict__ Wb2r) {
  int tid = blockIdx.x * 256 + threadIdx.x;
  if (tid < 128 * 256) {
    int n = tid >> 8, k = tid & 255;
    float v = (k < 128) ? W1l[n * 128 + k] : W1r[n * 128 + (k - 128)];
    Wb1[tid] = (ushort_t)f2bf(v);
  } else if (tid < 128 * 256 + 64 * 128) {
    int t2 = tid - 128 * 256;
    Wb2l[t2] = (ushort_t)f2bf(W2l[t2]);
  } else if (tid < 128 * 256 + 2 * 64 * 128) {
    int t2 = tid - 128 * 256 - 64 * 128;
    Wb2r[t2] = (ushort_t)f2bf(W2r[t2]);
  }
}

// ---------------------------------------------------------------------------
// Layer 1 MFMA GEMM, 4x M-blocked: wave = 64 rows x 128 cols, block = 2 waves.
// Per ks: 4 A-frag loads + 8 B-frag loads -> 32 MFMAs (2.7 MFMA/load).
// Epilogue: h bf16 + fused BN column sums (LDS + atomics).
// ---------------------------------------------------------------------------
__global__ __launch_bounds__(128, 2) void gemm1_mfma(const ushort_t* __restrict__ s,
                                                     const ushort_t* __restrict__ x,
                                                     const ushort_t* __restrict__ Wb,
                                                     const float* __restrict__ b1l,
                                                     ushort_t* __restrict__ h,
                                                     float* __restrict__ sums,
                                                     float* __restrict__ sumsq) {
  __shared__ float sred[2][2][DH];
  int w = threadIdx.x >> 6;
  int l = threadIdx.x & 63;
  int m = l & 15;
  int q = l >> 4;
  int rowblk = blockIdx.x * 128 + w * 64;
  int rl[4];
#pragma unroll
  for (int mt = 0; mt < 4; mt++) {
    int row = rowblk + mt * 16 + m;
    rl[mt] = row < NN ? row : NN - 1;
  }
  f32x4 acc[4][8];
#pragma unroll
  for (int mt = 0; mt < 4; mt++)
#pragma unroll
    for (int t = 0; t < 8; t++) acc[mt][t] = (f32x4){0.f, 0.f, 0.f, 0.f};
#pragma unroll
  for (int ks = 0; ks < 8; ks++) {
    const ushort_t* base = (ks < 4) ? s : x;
    int off = (ks & 3) * 32 + q * 8;
    bf16x8 a[4];
#pragma unroll
    for (int mt = 0; mt < 4; mt++)
      a[mt] = *(const bf16x8*)(base + (size_t)rl[mt] * DH + off);
#pragma unroll
    for (int t = 0; t < 8; t++) {
      bf16x8 bf = *(const bf16x8*)(Wb + (size_t)(t * 16 + m) * 256 + ks * 32 + q * 8);
#pragma unroll
      for (int mt = 0; mt < 4; mt++)
        acc[mt][t] = __builtin_amdgcn_mfma_f32_16x16x32_bf16(a[mt], bf, acc[mt][t], 0, 0, 0);
    }
  }
  // C layout: col = t*16 + m, row = rowblk + mt*16 + q*4 + r
  float psum[8], psq[8];
#pragma unroll
  for (int t = 0; t < 8; t++) { psum[t] = 0.f; psq[t] = 0.f; }
#pragma unroll
  for (int t = 0; t < 8; t++) {
    float bias = b1l[t * 16 + m];
#pragma unroll
    for (int mt = 0; mt < 4; mt++) {
#pragma unroll
      for (int r = 0; r < 4; r++) {
        int rr = rowblk + mt * 16 + q * 4 + r;
        if (rr < NN) {
          float vv = acc[mt][t][r] + bias;
          h[(size_t)rr * DH + t * 16 + m] = (ushort_t)f2bf(vv);
          psum[t] += vv;
          psq[t] += vv * vv;
        }
      }
    }
  }
#pragma unroll
  for (int t = 0; t < 8; t++) {
    psum[t] += __shfl_xor(psum[t], 16, 64);
    psum[t] += __shfl_xor(psum[t], 32, 64);
    psq[t] += __shfl_xor(psq[t], 16, 64);
    psq[t] += __shfl_xor(psq[t], 32, 64);
  }
  if (q == 0) {
#pragma unroll
    for (int t = 0; t < 8; t++) {
      sred[0][w][t * 16 + m] = psum[t];
      sred[1][w][t * 16 + m] = psq[t];
    }
  }
  __syncthreads();
  int tid = threadIdx.x;
  atomicAdd(&sums[tid], sred[0][0][tid] + sred[0][1][tid]);
  atomicAdd(&sumsq[tid], sred[1][0][tid] + sred[1][1][tid]);
}

// stats -> per-column scale/shift (tiny).
__global__ __launch_bounds__(128) void bn_prep_kernel(const float* __restrict__ sums,
                                                      const float* __restrict__ sumsq,
                                                      const float* __restrict__ gamma,
                                                      const float* __restrict__ beta,
                                                      float* __restrict__ scl,
                                                      float* __restrict__ sh) {
  int c = threadIdx.x;
  float mean = sums[c] * (1.0f / NN);
  float var = sumsq[c] * (1.0f / NN) - mean * mean;
  float s = gamma[c] * rsqrtf(var + 1e-5f);
  scl[c] = s;
  sh[c] = beta[c] - mean * s;
}

// BN+ReLU A-fragment from bf16 h with preloaded scl/sh vectors.
__device__ __forceinline__ bf16x8 bn_frag2(bf16x8 hv, float4 s0, float4 s1,
                                           float4 h0, float4 h1) {
  bf16x8 af;
  af[0] = f2bf(fmaxf(bf2f(hv[0]) * s0.x + h0.x, 0.f));
  af[1] = f2bf(fmaxf(bf2f(hv[1]) * s0.y + h0.y, 0.f));
  af[2] = f2bf(fmaxf(bf2f(hv[2]) * s0.z + h0.z, 0.f));
  af[3] = f2bf(fmaxf(bf2f(hv[3]) * s0.w + h0.w, 0.f));
  af[4] = f2bf(fmaxf(bf2f(hv[4]) * s1.x + h1.x, 0.f));
  af[5] = f2bf(fmaxf(bf2f(hv[5]) * s1.y + h1.y, 0.f));
  af[6] = f2bf(fmaxf(bf2f(hv[6]) * s1.z + h1.z, 0.f));
  af[7] = f2bf(fmaxf(bf2f(hv[7]) * s1.w + h1.w, 0.f));
  return af;
}

// ---------------------------------------------------------------------------
// z = relu(bn(h)) @ W2l^T  [N x 64] bf16, K=128. 4x M-blocked.
// ---------------------------------------------------------------------------
__global__ __launch_bounds__(128, 2) void z_mfma(const ushort_t* __restrict__ hin,
                                                 const float* __restrict__ scl,
                                                 const float* __restrict__ sh,
                                                 const ushort_t* __restrict__ Wb2l,
                                                 ushort_t* __restrict__ z) {
  int w = threadIdx.x >> 6;
  int l = threadIdx.x & 63;
  int m = l & 15;
  int q = l >> 4;
  int rowblk = blockIdx.x * 128 + w * 64;
  int rl[4];
#pragma unroll
  for (int mt = 0; mt < 4; mt++) {
    int row = rowblk + mt * 16 + m;
    rl[mt] = row < NN ? row : NN - 1;
  }
  f32x4 acc[4][4];
#pragma unroll
  for (int mt = 0; mt < 4; mt++)
#pragma unroll
    for (int t = 0; t < 4; t++) acc[mt][t] = (f32x4){0.f, 0.f, 0.f, 0.f};
#pragma unroll
  for (int ks = 0; ks < 4; ks++) {
    int k0 = ks * 32 + q * 8;
    float4 s0 = ((const float4*)(scl + k0))[0];
    float4 s1 = ((const float4*)(scl + k0))[1];
    float4 h0 = ((const float4*)(sh + k0))[0];
    float4 h1 = ((const float4*)(sh + k0))[1];
    bf16x8 bfr[4];
#pragma unroll
    for (int t = 0; t < 4; t++)
      bfr[t] = *(const bf16x8*)(Wb2l + (size_t)(t * 16 + m) * DH + k0);
#pragma unroll
    for (int mt = 0; mt < 4; mt++) {
      bf16x8 hv = *(const bf16x8*)(hin + (size_t)rl[mt] * DH + k0);
      bf16x8 af = bn_frag2(hv, s0, s1, h0, h1);
#pragma unroll
      for (int t = 0; t < 4; t++)
        acc[mt][t] = __builtin_amdgcn_mfma_f32_16x16x32_bf16(af, bfr[t], acc[mt][t], 0, 0, 0);
    }
  }
#pragma unroll
  for (int mt = 0; mt < 4; mt++)
#pragma unroll
    for (int t = 0; t < 4; t++)
#pragma unroll
      for (int r = 0; r < 4; r++) {
        int rr = rowblk + mt * 16 + q * 4 + r;
        if (rr < NN) z[(size_t)rr * DOUT + t * 16 + m] = (ushort_t)f2bf(acc[mt][t][r]);
      }
}

// ---------------------------------------------------------------------------
// Layer 2: out = zagg + relu(bn(h)) @ W2r^T + b2, log_softmax. 4x M-blocked.
// ---------------------------------------------------------------------------
__global__ __launch_bounds__(128, 2) void gemm2_mfma(const ushort_t* __restrict__ hin,
                                                     const float* __restrict__ scl,
                                                     const float* __restrict__ sh,
                                                     const ushort_t* __restrict__ zagg,
                                                     const ushort_t* __restrict__ Wb2r,
                                                     const float* __restrict__ b2l,
                                                     float* __restrict__ out) {
  int w = threadIdx.x >> 6;
  int l = threadIdx.x & 63;
  int m = l & 15;
  int q = l >> 4;
  int rowblk = blockIdx.x * 128 + w * 64;
  int rl[4];
#pragma unroll
  for (int mt = 0; mt < 4; mt++) {
    int row = rowblk + mt * 16 + m;
    rl[mt] = row < NN ? row : NN - 1;
  }
  f32x4 acc[4][4];
#pragma unroll
  for (int mt = 0; mt < 4; mt++)
#pragma unroll
    for (int t = 0; t < 4; t++) acc[mt][t] = (f32x4){0.f, 0.f, 0.f, 0.f};
#pragma unroll
  for (int ks = 0; ks < 4; ks++) {
    int k0 = ks * 32 + q * 8;
    float4 s0 = ((const float4*)(scl + k0))[0];
    float4 s1 = ((const float4*)(scl + k0))[1];
    float4 h0 = ((const float4*)(sh + k0))[0];
    float4 h1 = ((const float4*)(sh + k0))[1];
    bf16x8 bfr[4];
#pragma unroll
    for (int t = 0; t < 4; t++)
      bfr[t] = *(const bf16x8*)(Wb2r + (size_t)(t * 16 + m) * DH + k0);
#pragma unroll
    for (int mt = 0; mt < 4; mt++) {
      bf16x8 hv = *(const bf16x8*)(hin + (size_t)rl[mt] * DH + k0);
      bf16x8 af = bn_frag2(hv, s0, s1, h0, h1);
#pragma unroll
      for (int t = 0; t < 4; t++)
        acc[mt][t] = __builtin_amdgcn_mfma_f32_16x16x32_bf16(af, bfr[t], acc[mt][t], 0, 0, 0);
    }
  }
#pragma unroll
  for (int mt = 0; mt < 4; mt++) {
    float v[4][4];
#pragma unroll
    for (int t = 0; t < 4; t++) {
      float bias = b2l[t * 16 + m];
#pragma unroll
      for (int r = 0; r < 4; r++) {
        int rr = rowblk + mt * 16 + q * 4 + r;
        float zg = (rr < NN) ? bf2f((short)zagg[(size_t)rr * DOUT + t * 16 + m]) : 0.f;
        v[t][r] = acc[mt][t][r] + zg + bias;
      }
    }
#pragma unroll
    for (int r = 0; r < 4; r++) {
      float mx = fmaxf(fmaxf(v[0][r], v[1][r]), fmaxf(v[2][r], v[3][r]));
      mx = fmaxf(mx, __shfl_xor(mx, 1, 64));
      mx = fmaxf(mx, __shfl_xor(mx, 2, 64));
      mx = fmaxf(mx, __shfl_xor(mx, 4, 64));
      mx = fmaxf(mx, __shfl_xor(mx, 8, 64));
      float se = __expf(v[0][r] - mx) + __expf(v[1][r] - mx) +
                 __expf(v[2][r] - mx) + __expf(v[3][r] - mx);
      se += __shfl_xor(se, 1, 64);
      se += __shfl_xor(se, 2, 64);
      se += __shfl_xor(se, 4, 64);
      se += __shfl_xor(se, 8, 64);
      float lse = mx + logf(se);
      int rr = rowblk + mt * 16 + q * 4 + r;
      if (rr < NN) {
#pragma unroll
        for (int t = 0; t < 4; t++)
          out[(size_t)rr * DOUT + t * 16 + m] = v[t][r] - lse;
      }
    }
  }
}

// ---------------------------------------------------------------------------
extern "C" void kernel_launch(void* const* d_in, const int* in_sizes, int n_in,
                              void* d_out, int out_size, void* d_ws, size_t ws_size,
                              hipStream_t stream) {
  const float* x = (const float*)d_in[0];
  const int* ei = (const int*)d_in[1];
  const float* W1l = (const float*)d_in[2];
  const float* b1l = (const float*)d_in[3];
  const float* W1r = (const float*)d_in[4];
  const float* gamma = (const float*)d_in[5];
  const float* beta = (const float*)d_in[6];
  const float* W2l = (const float*)d_in[7];
  const float* b2l = (const float*)d_in[8];
  const float* W2r = (const float*)d_in[9];
  float* out = (float*)d_out;
  int E = in_sizes[1] / 2;
  int nblkg = (NN + 127) / 128;

  // workspace (~110 MB):
  //   u0: union { edges int2[E] | z_bf16[N*64] + zagg_bf16[N*64] } 25.6 MB
  //   x_bf16 | s_bf16 | h_bf16 | degi | row_ptr | col | stats | flag | W tables
  char* p = (char*)d_ws;
  int2* edges = (int2*)p;
  ushort_t* z_bf = (ushort_t*)p;
  ushort_t* zagg_bf = z_bf + (size_t)NN * DOUT;
  p += (size_t)NN * DOUT * 2 * sizeof(ushort_t);
  ushort_t* x_bf = (ushort_t*)p;  p += (size_t)NN * DH * sizeof(ushort_t);
  ushort_t* s_bf = (ushort_t*)p;  p += (size_t)NN * DH * sizeof(ushort_t);
  ushort_t* h_bf = (ushort_t*)p;  p += (size_t)NN * DH * sizeof(ushort_t);
  int* degi = (int*)p;            p += NN * sizeof(int);
  int* row_ptr = (int*)p;         p += NN * sizeof(int);
  int* col = (int*)p;             p += (size_t)E * sizeof(int);
  float* sums = (float*)p;        p += DH * sizeof(float);
  float* sumsq = (float*)p;       p += DH * sizeof(float);
  float* scl = (float*)p;         p += DH * sizeof(float);
  float* sh = (float*)p;          p += DH * sizeof(float);
  int* flag = (int*)p;            p += 4 * sizeof(int);
  ushort_t* Wb1 = (ushort_t*)p;   p += 128 * 256 * sizeof(ushort_t);
  ushort_t* Wb2l = (ushort_t*)p;  p += 64 * 128 * sizeof(ushort_t);
  ushort_t* Wb2r = (ushort_t*)p;

  hipMemsetAsync(degi, 0, NN * sizeof(int), stream);
  hipMemsetAsync(sums, 0, 2 * DH * sizeof(float), stream);

  detect_kernel<<<1, 256, 0, stream>>>(ei, E, flag);
  convw_kernel<<<192, 256, 0, stream>>>(W1l, W1r, W2l, W2r, Wb1, Wb2l, Wb2r);
  convx_kernel<<<(NN * DH / 8 + 255) / 256, 256, 0, stream>>>(x, x_bf);
  convert_deg_kernel<<<(E + 255) / 256, 256, 0, stream>>>(ei, E, flag, edges, degi);
  scan_kernel<<<1, 1024, 0, stream>>>(degi, row_ptr);
  int nb = (E + 255) / 256;
  fill_kernel<<<FILL_PASSES * nb, 256, 0, stream>>>(edges, E, nb, row_ptr, col);
  gather128_kernel<<<(NN * 16 + 255) / 256, 256, 0, stream>>>(x_bf, col, row_ptr, degi, s_bf);
  gemm1_mfma<<<nblkg, 128, 0, stream>>>(s_bf, x_bf, Wb1, b1l, h_bf, sums, sumsq);
  bn_prep_kernel<<<1, 128, 0, stream>>>(sums, sumsq, gamma, beta, scl, sh);
  z_mfma<<<nblkg, 128, 0, stream>>>(h_bf, scl, sh, Wb2l, z_bf);
  gather64_kernel<<<(NN * 8 + 255) / 256, 256, 0, stream>>>(z_bf, col, row_ptr, degi, zagg_bf);
  gemm2_mfma<<<nblkg, 128, 0, stream>>>(h_bf, scl, sh, zagg_bf, Wb2r, b2l, out);
}

// Round 8
// 487.395 us; speedup vs baseline: 2.1892x; 1.0182x over previous
//
#include <hip/hip_runtime.h>
#include <math.h>

#define NN 100000
#define DH 128
#define DOUT 64
#define FILL_PASSES 8   // one window per XCD; pass = blockIdx & 7 pins window->XCD

typedef __attribute__((ext_vector_type(8))) short bf16x8;
typedef __attribute__((ext_vector_type(4))) float f32x4;
typedef unsigned short ushort_t;

__device__ __forceinline__ short f2bf(float f) {
  unsigned u = __float_as_uint(f);
  unsigned r = (u + 0x7fffu + ((u >> 16) & 1u)) >> 16;
  return (short)r;
}
__device__ __forceinline__ float bf2f(short b) {
  return __uint_as_float(((unsigned)(unsigned short)b) << 16);
}

// ---------------------------------------------------------------------------
// Edge-index dtype detector (int64 reference vs int32 harness doc).
// ---------------------------------------------------------------------------
__global__ __launch_bounds__(256) void detect_kernel(const int* __restrict__ ei, int E,
                                                     int* __restrict__ flag) {
  const long long* e64 = (const long long*)ei;
  int lim = E < 1024 ? E : 1024;
  int ok = 1;
  for (int i = threadIdx.x; i < lim; i += 256) {
    long long v = e64[i];
    if (v < 0 || v >= NN) ok = 0;
  }
  __shared__ int s_ok;
  if (threadIdx.x == 0) s_ok = 1;
  __syncthreads();
  if (!ok) atomicAnd(&s_ok, 0);
  __syncthreads();
  if (threadIdx.x == 0) *flag = s_ok;
}

__device__ __forceinline__ int edge_at(const int* __restrict__ ei, int is64, size_t pos) {
  return is64 ? (int)(((const long long*)ei)[pos]) : ei[pos];
}

// ---------------------------------------------------------------------------
// x (fp32) -> x_bf16, 8 elems/thread.
// ---------------------------------------------------------------------------
__global__ __launch_bounds__(256) void convx_kernel(const float* __restrict__ x,
                                                    ushort_t* __restrict__ xb) {
  size_t i = ((size_t)blockIdx.x * 256 + threadIdx.x) * 8;
  if (i >= (size_t)NN * DH) return;
  float4 f0 = ((const float4*)(x + i))[0];
  float4 f1 = ((const float4*)(x + i))[1];
  bf16x8 o;
  o[0] = f2bf(f0.x); o[1] = f2bf(f0.y); o[2] = f2bf(f0.z); o[3] = f2bf(f0.w);
  o[4] = f2bf(f1.x); o[5] = f2bf(f1.y); o[6] = f2bf(f1.z); o[7] = f2bf(f1.w);
  *(bf16x8*)(xb + i) = o;
}

// ---------------------------------------------------------------------------
// One pass over edges: pack to int2 {src,dst} AND build degree histogram.
// ---------------------------------------------------------------------------
__global__ __launch_bounds__(256) void convert_deg_kernel(const int* __restrict__ ei, int E,
                                                          const int* __restrict__ flag,
                                                          int2* __restrict__ edges,
                                                          int* __restrict__ degi) {
  int e = blockIdx.x * 256 + threadIdx.x;
  if (e >= E) return;
  int is64 = *flag;
  int src = edge_at(ei, is64, (size_t)e);
  int dst = edge_at(ei, is64, (size_t)E + e);
  edges[e] = make_int2(src, dst);
  atomicAdd(&degi[dst], 1);
}

// ---------------------------------------------------------------------------
// Exclusive scan of degi -> row_ptr. Single block, 1024 thr x 4 elems/thr.
// ---------------------------------------------------------------------------
__global__ __launch_bounds__(1024) void scan_kernel(const int* __restrict__ degi,
                                                    int* __restrict__ row_ptr) {
  __shared__ int warp_sums[16];
  __shared__ int s_offset;
  int lane = threadIdx.x & 63;
  int wid = threadIdx.x >> 6;
  if (threadIdx.x == 0) s_offset = 0;
  __syncthreads();
  for (int base = 0; base < NN; base += 4096) {
    int i0 = base + threadIdx.x * 4;
    int v0 = (i0 + 0 < NN) ? degi[i0 + 0] : 0;
    int v1 = (i0 + 1 < NN) ? degi[i0 + 1] : 0;
    int v2 = (i0 + 2 < NN) ? degi[i0 + 2] : 0;
    int v3 = (i0 + 3 < NN) ? degi[i0 + 3] : 0;
    int tot = v0 + v1 + v2 + v3;
    int sv = tot;
#pragma unroll
    for (int o = 1; o < 64; o <<= 1) {
      int t = __shfl_up(sv, o, 64);
      if (lane >= o) sv += t;
    }
    if (lane == 63) warp_sums[wid] = sv;
    __syncthreads();
    if (wid == 0 && lane < 16) {
      int ws = warp_sums[lane];
#pragma unroll
      for (int o = 1; o < 16; o <<= 1) {
        int t = __shfl_up(ws, o, 16);
        if (lane >= o) ws += t;
      }
      warp_sums[lane] = ws;
    }
    __syncthreads();
    int wave_off = (wid == 0) ? 0 : warp_sums[wid - 1];
    int excl = s_offset + wave_off + sv - tot;
    if (i0 + 0 < NN) row_ptr[i0 + 0] = excl;
    if (i0 + 1 < NN) row_ptr[i0 + 1] = excl + v0;
    if (i0 + 2 < NN) row_ptr[i0 + 2] = excl + v0 + v1;
    if (i0 + 3 < NN) row_ptr[i0 + 3] = excl + v0 + v1 + v2;
    __syncthreads();
    if (threadIdx.x == 1023) s_offset = excl + tot;
    __syncthreads();
  }
}

// ---------------------------------------------------------------------------
// XCD-exclusive windowed CSR fill. pass = blockIdx & 7: consecutive blockIdx
// round-robin across the 8 XCDs, so all writes into a given dst-window come
// from ONE XCD -> col lines fill densely in that XCD's L2, single writeback.
// (Round-4's shared-window version still wrote 93 MB: 8 XCDs held partial
// dirty copies of every line.) row_ptr doubles as cursor.
// ---------------------------------------------------------------------------
__global__ __launch_bounds__(256) void fill_kernel(const int2* __restrict__ edges, int E,
                                                   int* __restrict__ row_ptr,
                                                   int* __restrict__ col) {
  int pass = blockIdx.x & 7;
  int blk = blockIdx.x >> 3;
  int e = blk * 256 + threadIdx.x;
  if (e >= E) return;
  int2 sd = edges[e];
  const int WIN = (NN + FILL_PASSES - 1) / FILL_PASSES;
  if ((unsigned)(sd.y - pass * WIN) < (unsigned)WIN) {
    int pos = atomicAdd(&row_ptr[sd.y], 1);
    col[pos] = sd.x;
  }
}

// ---------------------------------------------------------------------------
// Gather mean-agg, 128-dim bf16 rows: 16 lanes/node, bf16x8 (16B) per lane.
// ---------------------------------------------------------------------------
__global__ __launch_bounds__(256) void gather128_kernel(const ushort_t* __restrict__ feat,
                                                        const int* __restrict__ col,
                                                        const int* __restrict__ row_end,
                                                        const int* __restrict__ degi,
                                                        ushort_t* __restrict__ outp) {
  int tid = blockIdx.x * 256 + threadIdx.x;
  int n = tid >> 4;
  if (n >= NN) return;
  int g = tid & 15;
  int d = degi[n];
  int start = row_end[n] - d;
  float acc[8];
#pragma unroll
  for (int j = 0; j < 8; j++) acc[j] = 0.f;
#pragma unroll 4
  for (int i = 0; i < d; i++) {
    int src = col[start + i];
    bf16x8 v = *(const bf16x8*)(feat + (size_t)src * DH + g * 8);
#pragma unroll
    for (int j = 0; j < 8; j++) acc[j] += bf2f(v[j]);
  }
  float inv = 1.0f / (float)max(d, 1);
  bf16x8 o;
#pragma unroll
  for (int j = 0; j < 8; j++) o[j] = f2bf(acc[j] * inv);
  *(bf16x8*)(outp + (size_t)n * DH + g * 8) = o;
}

// ---------------------------------------------------------------------------
// Gather mean-agg, 64-dim bf16 rows: 8 lanes/node, bf16x8 per lane.
// ---------------------------------------------------------------------------
__global__ __launch_bounds__(256) void gather64_kernel(const ushort_t* __restrict__ feat,
                                                       const int* __restrict__ col,
                                                       const int* __restrict__ row_end,
                                                       const int* __restrict__ degi,
                                                       ushort_t* __restrict__ outp) {
  int tid = blockIdx.x * 256 + threadIdx.x;
  int n = tid >> 3;
  if (n >= NN) return;
  int g = tid & 7;
  int d = degi[n];
  int start = row_end[n] - d;
  float acc[8];
#pragma unroll
  for (int j = 0; j < 8; j++) acc[j] = 0.f;
#pragma unroll 4
  for (int i = 0; i < d; i++) {
    int src = col[start + i];
    bf16x8 v = *(const bf16x8*)(feat + (size_t)src * DOUT + g * 8);
#pragma unroll
    for (int j = 0; j < 8; j++) acc[j] += bf2f(v[j]);
  }
  float inv = 1.0f / (float)max(d, 1);
  bf16x8 o;
#pragma unroll
  for (int j = 0; j < 8; j++) o[j] = f2bf(acc[j] * inv);
  *(bf16x8*)(outp + (size_t)n * DOUT + g * 8) = o;
}

// ---------------------------------------------------------------------------
// Weight conversion: Wb1[128][256]=[W1l|W1r], Wb2l[64][128], Wb2r[64][128].
// ---------------------------------------------------------------------------
__global__ __launch_bounds__(256) void convw_kernel(const float* __restrict__ W1l,
                                                    const float* __restrict__ W1r,
                                                    const float* __restrict__ W2l,
                                                    const float* __restrict__ W2r,
                                                    ushort_t* __restrict__ Wb1,
                                                    ushort_t* __restrict__ Wb2l,
                                                    ushort_t* __restrict__ Wb2r) {
  int tid = blockIdx.x * 256 + threadIdx.x;
  if (tid < 128 * 256) {
    int n = tid >> 8, k = tid & 255;
    float v = (k < 128) ? W1l[n * 128 + k] : W1r[n * 128 + (k - 128)];
    Wb1[tid] = (ushort_t)f2bf(v);
  } else if (tid < 128 * 256 + 64 * 128) {
    int t2 = tid - 128 * 256;
    Wb2l[t2] = (ushort_t)f2bf(W2l[t2]);
  } else if (tid < 128 * 256 + 2 * 64 * 128) {
    int t2 = tid - 128 * 256 - 64 * 128;
    Wb2r[t2] = (ushort_t)f2bf(W2r[t2]);
  }
}

// ---------------------------------------------------------------------------
// Layer 1 MFMA GEMM, 4x M-blocked: wave = 64 rows x 128 cols, block = 2 waves.
// Epilogue: h bf16 + fused BN column sums (LDS + atomics).
// ---------------------------------------------------------------------------
__global__ __launch_bounds__(128, 2) void gemm1_mfma(const ushort_t* __restrict__ s,
                                                     const ushort_t* __restrict__ x,
                                                     const ushort_t* __restrict__ Wb,
                                                     const float* __restrict__ b1l,
                                                     ushort_t* __restrict__ h,
                                                     float* __restrict__ sums,
                                                     float* __restrict__ sumsq) {
  __shared__ float sred[2][2][DH];
  int w = threadIdx.x >> 6;
  int l = threadIdx.x & 63;
  int m = l & 15;
  int q = l >> 4;
  int rowblk = blockIdx.x * 128 + w * 64;
  int rl[4];
#pragma unroll
  for (int mt = 0; mt < 4; mt++) {
    int row = rowblk + mt * 16 + m;
    rl[mt] = row < NN ? row : NN - 1;
  }
  f32x4 acc[4][8];
#pragma unroll
  for (int mt = 0; mt < 4; mt++)
#pragma unroll
    for (int t = 0; t < 8; t++) acc[mt][t] = (f32x4){0.f, 0.f, 0.f, 0.f};
#pragma unroll
  for (int ks = 0; ks < 8; ks++) {
    const ushort_t* base = (ks < 4) ? s : x;
    int off = (ks & 3) * 32 + q * 8;
    bf16x8 a[4];
#pragma unroll
    for (int mt = 0; mt < 4; mt++)
      a[mt] = *(const bf16x8*)(base + (size_t)rl[mt] * DH + off);
#pragma unroll
    for (int t = 0; t < 8; t++) {
      bf16x8 bf = *(const bf16x8*)(Wb + (size_t)(t * 16 + m) * 256 + ks * 32 + q * 8);
#pragma unroll
      for (int mt = 0; mt < 4; mt++)
        acc[mt][t] = __builtin_amdgcn_mfma_f32_16x16x32_bf16(a[mt], bf, acc[mt][t], 0, 0, 0);
    }
  }
  // C layout: col = t*16 + m, row = rowblk + mt*16 + q*4 + r
  float psum[8], psq[8];
#pragma unroll
  for (int t = 0; t < 8; t++) { psum[t] = 0.f; psq[t] = 0.f; }
#pragma unroll
  for (int t = 0; t < 8; t++) {
    float bias = b1l[t * 16 + m];
#pragma unroll
    for (int mt = 0; mt < 4; mt++) {
#pragma unroll
      for (int r = 0; r < 4; r++) {
        int rr = rowblk + mt * 16 + q * 4 + r;
        if (rr < NN) {
          float vv = acc[mt][t][r] + bias;
          h[(size_t)rr * DH + t * 16 + m] = (ushort_t)f2bf(vv);
          psum[t] += vv;
          psq[t] += vv * vv;
        }
      }
    }
  }
#pragma unroll
  for (int t = 0; t < 8; t++) {
    psum[t] += __shfl_xor(psum[t], 16, 64);
    psum[t] += __shfl_xor(psum[t], 32, 64);
    psq[t] += __shfl_xor(psq[t], 16, 64);
    psq[t] += __shfl_xor(psq[t], 32, 64);
  }
  if (q == 0) {
#pragma unroll
    for (int t = 0; t < 8; t++) {
      sred[0][w][t * 16 + m] = psum[t];
      sred[1][w][t * 16 + m] = psq[t];
    }
  }
  __syncthreads();
  int tid = threadIdx.x;
  atomicAdd(&sums[tid], sred[0][0][tid] + sred[0][1][tid]);
  atomicAdd(&sumsq[tid], sred[1][0][tid] + sred[1][1][tid]);
}

// stats -> per-column scale/shift (tiny).
__global__ __launch_bounds__(128) void bn_prep_kernel(const float* __restrict__ sums,
                                                      const float* __restrict__ sumsq,
                                                      const float* __restrict__ gamma,
                                                      const float* __restrict__ beta,
                                                      float* __restrict__ scl,
                                                      float* __restrict__ sh) {
  int c = threadIdx.x;
  float mean = sums[c] * (1.0f / NN);
  float var = sumsq[c] * (1.0f / NN) - mean * mean;
  float s = gamma[c] * rsqrtf(var + 1e-5f);
  scl[c] = s;
  sh[c] = beta[c] - mean * s;
}

// BN+ReLU A-fragment from bf16 h with preloaded scl/sh vectors.
__device__ __forceinline__ bf16x8 bn_frag2(bf16x8 hv, float4 s0, float4 s1,
                                           float4 h0, float4 h1) {
  bf16x8 af;
  af[0] = f2bf(fmaxf(bf2f(hv[0]) * s0.x + h0.x, 0.f));
  af[1] = f2bf(fmaxf(bf2f(hv[1]) * s0.y + h0.y, 0.f));
  af[2] = f2bf(fmaxf(bf2f(hv[2]) * s0.z + h0.z, 0.f));
  af[3] = f2bf(fmaxf(bf2f(hv[3]) * s0.w + h0.w, 0.f));
  af[4] = f2bf(fmaxf(bf2f(hv[4]) * s1.x + h1.x, 0.f));
  af[5] = f2bf(fmaxf(bf2f(hv[5]) * s1.y + h1.y, 0.f));
  af[6] = f2bf(fmaxf(bf2f(hv[6]) * s1.z + h1.z, 0.f));
  af[7] = f2bf(fmaxf(bf2f(hv[7]) * s1.w + h1.w, 0.f));
  return af;
}

// ---------------------------------------------------------------------------
// z = relu(bn(h)) @ W2l^T  [N x 64] bf16, K=128. 4x M-blocked.
// ---------------------------------------------------------------------------
__global__ __launch_bounds__(128, 2) void z_mfma(const ushort_t* __restrict__ hin,
                                                 const float* __restrict__ scl,
                                                 const float* __restrict__ sh,
                                                 const ushort_t* __restrict__ Wb2l,
                                                 ushort_t* __restrict__ z) {
  int w = threadIdx.x >> 6;
  int l = threadIdx.x & 63;
  int m = l & 15;
  int q = l >> 4;
  int rowblk = blockIdx.x * 128 + w * 64;
  int rl[4];
#pragma unroll
  for (int mt = 0; mt < 4; mt++) {
    int row = rowblk + mt * 16 + m;
    rl[mt] = row < NN ? row : NN - 1;
  }
  f32x4 acc[4][4];
#pragma unroll
  for (int mt = 0; mt < 4; mt++)
#pragma unroll
    for (int t = 0; t < 4; t++) acc[mt][t] = (f32x4){0.f, 0.f, 0.f, 0.f};
#pragma unroll
  for (int ks = 0; ks < 4; ks++) {
    int k0 = ks * 32 + q * 8;
    float4 s0 = ((const float4*)(scl + k0))[0];
    float4 s1 = ((const float4*)(scl + k0))[1];
    float4 h0 = ((const float4*)(sh + k0))[0];
    float4 h1 = ((const float4*)(sh + k0))[1];
    bf16x8 bfr[4];
#pragma unroll
    for (int t = 0; t < 4; t++)
      bfr[t] = *(const bf16x8*)(Wb2l + (size_t)(t * 16 + m) * DH + k0);
#pragma unroll
    for (int mt = 0; mt < 4; mt++) {
      bf16x8 hv = *(const bf16x8*)(hin + (size_t)rl[mt] * DH + k0);
      bf16x8 af = bn_frag2(hv, s0, s1, h0, h1);
#pragma unroll
      for (int t = 0; t < 4; t++)
        acc[mt][t] = __builtin_amdgcn_mfma_f32_16x16x32_bf16(af, bfr[t], acc[mt][t], 0, 0, 0);
    }
  }
#pragma unroll
  for (int mt = 0; mt < 4; mt++)
#pragma unroll
    for (int t = 0; t < 4; t++)
#pragma unroll
      for (int r = 0; r < 4; r++) {
        int rr = rowblk + mt * 16 + q * 4 + r;
        if (rr < NN) z[(size_t)rr * DOUT + t * 16 + m] = (ushort_t)f2bf(acc[mt][t][r]);
      }
}

// ---------------------------------------------------------------------------
// Layer 2: out = zagg + relu(bn(h)) @ W2r^T + b2, log_softmax. 4x M-blocked.
// ---------------------------------------------------------------------------
__global__ __launch_bounds__(128, 2) void gemm2_mfma(const ushort_t* __restrict__ hin,
                                                     const float* __restrict__ scl,
                                                     const float* __restrict__ sh,
                                                     const ushort_t* __restrict__ zagg,
                                                     const ushort_t* __restrict__ Wb2r,
                                                     const float* __restrict__ b2l,
                                                     float* __restrict__ out) {
  int w = threadIdx.x >> 6;
  int l = threadIdx.x & 63;
  int m = l & 15;
  int q = l >> 4;
  int rowblk = blockIdx.x * 128 + w * 64;
  int rl[4];
#pragma unroll
  for (int mt = 0; mt < 4; mt++) {
    int row = rowblk + mt * 16 + m;
    rl[mt] = row < NN ? row : NN - 1;
  }
  f32x4 acc[4][4];
#pragma unroll
  for (int mt = 0; mt < 4; mt++)
#pragma unroll
    for (int t = 0; t < 4; t++) acc[mt][t] = (f32x4){0.f, 0.f, 0.f, 0.f};
#pragma unroll
  for (int ks = 0; ks < 4; ks++) {
    int k0 = ks * 32 + q * 8;
    float4 s0 = ((const float4*)(scl + k0))[0];
    float4 s1 = ((const float4*)(scl + k0))[1];
    float4 h0 = ((const float4*)(sh + k0))[0];
    float4 h1 = ((const float4*)(sh + k0))[1];
    bf16x8 bfr[4];
#pragma unroll
    for (int t = 0; t < 4; t++)
      bfr[t] = *(const bf16x8*)(Wb2r + (size_t)(t * 16 + m) * DH + k0);
#pragma unroll
    for (int mt = 0; mt < 4; mt++) {
      bf16x8 hv = *(const bf16x8*)(hin + (size_t)rl[mt] * DH + k0);
      bf16x8 af = bn_frag2(hv, s0, s1, h0, h1);
#pragma unroll
      for (int t = 0; t < 4; t++)
        acc[mt][t] = __builtin_amdgcn_mfma_f32_16x16x32_bf16(af, bfr[t], acc[mt][t], 0, 0, 0);
    }
  }
#pragma unroll
  for (int mt = 0; mt < 4; mt++) {
    float v[4][4];
#pragma unroll
    for (int t = 0; t < 4; t++) {
      float bias = b2l[t * 16 + m];
#pragma unroll
      for (int r = 0; r < 4; r++) {
        int rr = rowblk + mt * 16 + q * 4 + r;
        float zg = (rr < NN) ? bf2f((short)zagg[(size_t)rr * DOUT + t * 16 + m]) : 0.f;
        v[t][r] = acc[mt][t][r] + zg + bias;
      }
    }
#pragma unroll
    for (int r = 0; r < 4; r++) {
      float mx = fmaxf(fmaxf(v[0][r], v[1][r]), fmaxf(v[2][r], v[3][r]));
      mx = fmaxf(mx, __shfl_xor(mx, 1, 64));
      mx = fmaxf(mx, __shfl_xor(mx, 2, 64));
      mx = fmaxf(mx, __shfl_xor(mx, 4, 64));
      mx = fmaxf(mx, __shfl_xor(mx, 8, 64));
      float se = __expf(v[0][r] - mx) + __expf(v[1][r] - mx) +
                 __expf(v[2][r] - mx) + __expf(v[3][r] - mx);
      se += __shfl_xor(se, 1, 64);
      se += __shfl_xor(se, 2, 64);
      se += __shfl_xor(se, 4, 64);
      se += __shfl_xor(se, 8, 64);
      float lse = mx + logf(se);
      int rr = rowblk + mt * 16 + q * 4 + r;
      if (rr < NN) {
#pragma unroll
        for (int t = 0; t < 4; t++)
          out[(size_t)rr * DOUT + t * 16 + m] = v[t][r] - lse;
      }
    }
  }
}

// ---------------------------------------------------------------------------
extern "C" void kernel_launch(void* const* d_in, const int* in_sizes, int n_in,
                              void* d_out, int out_size, void* d_ws, size_t ws_size,
                              hipStream_t stream) {
  const float* x = (const float*)d_in[0];
  const int* ei = (const int*)d_in[1];
  const float* W1l = (const float*)d_in[2];
  const float* b1l = (const float*)d_in[3];
  const float* W1r = (const float*)d_in[4];
  const float* gamma = (const float*)d_in[5];
  const float* beta = (const float*)d_in[6];
  const float* W2l = (const float*)d_in[7];
  const float* b2l = (const float*)d_in[8];
  const float* W2r = (const float*)d_in[9];
  float* out = (float*)d_out;
  int E = in_sizes[1] / 2;
  int nblkg = (NN + 127) / 128;

  // workspace (~110 MB):
  //   u0: union { edges int2[E] | z_bf16[N*64] + zagg_bf16[N*64] } 25.6 MB
  //   x_bf16 | s_bf16 | h_bf16 | degi | row_ptr | col | stats | flag | W tables
  char* p = (char*)d_ws;
  int2* edges = (int2*)p;
  ushort_t* z_bf = (ushort_t*)p;
  ushort_t* zagg_bf = z_bf + (size_t)NN * DOUT;
  p += (size_t)NN * DOUT * 2 * sizeof(ushort_t);
  ushort_t* x_bf = (ushort_t*)p;  p += (size_t)NN * DH * sizeof(ushort_t);
  ushort_t* s_bf = (ushort_t*)p;  p += (size_t)NN * DH * sizeof(ushort_t);
  ushort_t* h_bf = (ushort_t*)p;  p += (size_t)NN * DH * sizeof(ushort_t);
  int* degi = (int*)p;            p += NN * sizeof(int);
  int* row_ptr = (int*)p;         p += NN * sizeof(int);
  int* col = (int*)p;             p += (size_t)E * sizeof(int);
  float* sums = (float*)p;        p += DH * sizeof(float);
  float* sumsq = (float*)p;       p += DH * sizeof(float);
  float* scl = (float*)p;         p += DH * sizeof(float);
  float* sh = (float*)p;          p += DH * sizeof(float);
  int* flag = (int*)p;            p += 4 * sizeof(int);
  ushort_t* Wb1 = (ushort_t*)p;   p += 128 * 256 * sizeof(ushort_t);
  ushort_t* Wb2l = (ushort_t*)p;  p += 64 * 128 * sizeof(ushort_t);
  ushort_t* Wb2r = (ushort_t*)p;

  hipMemsetAsync(degi, 0, NN * sizeof(int), stream);
  hipMemsetAsync(sums, 0, 2 * DH * sizeof(float), stream);

  detect_kernel<<<1, 256, 0, stream>>>(ei, E, flag);
  convw_kernel<<<192, 256, 0, stream>>>(W1l, W1r, W2l, W2r, Wb1, Wb2l, Wb2r);
  convx_kernel<<<(NN * DH / 8 + 255) / 256, 256, 0, stream>>>(x, x_bf);
  convert_deg_kernel<<<(E + 255) / 256, 256, 0, stream>>>(ei, E, flag, edges, degi);
  scan_kernel<<<1, 1024, 0, stream>>>(degi, row_ptr);
  int nb = (E + 255) / 256;
  fill_kernel<<<FILL_PASSES * nb, 256, 0, stream>>>(edges, E, row_ptr, col);
  gather128_kernel<<<(NN * 16 + 255) / 256, 256, 0, stream>>>(x_bf, col, row_ptr, degi, s_bf);
  gemm1_mfma<<<nblkg, 128, 0, stream>>>(s_bf, x_bf, Wb1, b1l, h_bf, sums, sumsq);
  bn_prep_kernel<<<1, 128, 0, stream>>>(sums, sumsq, gamma, beta, scl, sh);
  z_mfma<<<nblkg, 128, 0, stream>>>(h_bf, scl, sh, Wb2l, z_bf);
  gather64_kernel<<<(NN * 8 + 255) / 256, 256, 0, stream>>>(z_bf, col, row_ptr, degi, zagg_bf);
  gemm2_mfma<<<nblkg, 128, 0, stream>>>(h_bf, scl, sh, zagg_bf, Wb2r, b2l, out);
}